// Round 7
// baseline (528.528 us; speedup 1.0000x reference)
//
#include <hip/hip_runtime.h>
#include <stdint.h>

#define NEG_SLOPE 0.2f
#define BN_EPS 1e-5f

typedef __attribute__((ext_vector_type(8))) short bf16x8;
typedef __attribute__((ext_vector_type(4))) float f32x4;

// ---------------- bf16 helpers ----------------
__device__ __forceinline__ float bf2f(unsigned short u) {
  union { unsigned int i; float f; } v; v.i = ((unsigned int)u) << 16; return v.f;
}
__device__ __forceinline__ float asf(unsigned int u) {
  union { unsigned int i; float f; } v; v.i = u; return v.f;
}
__device__ __forceinline__ unsigned short f2bf(float f) {
  union { float f; unsigned int i; } v; v.f = f;
  unsigned int i = v.i;
  return (unsigned short)((i + 0x7fffu + ((i >> 16) & 1u)) >> 16);  // RNE
}
__device__ __forceinline__ float loadF(const void* p, long long i, int f32) {
  return f32 ? ((const float*)p)[i] : bf2f(((const unsigned short*)p)[i]);
}
__device__ __forceinline__ int edge_at(const void* ei, long long idx, int is64) {
  return is64 ? (int)((const long long*)ei)[idx] : ((const int*)ei)[idx];
}

// ---------------- input dtype detection ----------------
__global__ void detect_kernel(const unsigned short* __restrict__ x,
                              const int* __restrict__ ei32,
                              int* __restrict__ flags) {
  __shared__ int wild, oddnz;
  if (threadIdx.x == 0) { wild = 0; oddnz = 0; }
  __syncthreads();
  int lw = 0, lo = 0;
  for (int i = threadIdx.x; i < 4096; i += 256) {
    unsigned short u = x[i];
    int ex = (u >> 7) & 0xFF;
    if (ex >= 0x86) lw++;
    if (ei32[2 * i + 1] != 0) lo++;
  }
  if (lw) atomicAdd(&wild, lw);
  if (lo) atomicAdd(&oddnz, lo);
  __syncthreads();
  if (threadIdx.x == 0) { flags[0] = (wild > 64) ? 1 : 0; flags[1] = (oddnz == 0) ? 1 : 0; }
}

// ---------------- W preprocessing (one launch, 2 blocks = 2 layers) ----------------
// WTx [272 rows][64 k] bf16: rows 0..255 = W^T; 256..259 = Ws[h]; 260..263 = Wd[h]; 264..271 = 0.
__global__ __launch_bounds__(256) void wtrans_kernel(
    const void* __restrict__ W0, const void* __restrict__ as0, const void* __restrict__ ad0,
    const void* __restrict__ W1, const void* __restrict__ as1, const void* __restrict__ ad1,
    const int* __restrict__ flags,
    unsigned short* __restrict__ WTx0, unsigned short* __restrict__ WTx1) {
  const void* W = blockIdx.x ? W1 : W0;
  const void* asrc = blockIdx.x ? as1 : as0;
  const void* adst = blockIdx.x ? ad1 : ad0;
  unsigned short* WTx = blockIdx.x ? WTx1 : WTx0;
  int f32 = flags[0];
  __shared__ unsigned short Wl[64 * 258];  // W[k][c] bf16, pad 2
  int t = threadIdx.x;
  for (int i = t; i < 64 * 256; i += 256) {
    int k = i >> 8, c = i & 255;
    Wl[k * 258 + c] = f32 ? f2bf(((const float*)W)[i]) : ((const unsigned short*)W)[i];
  }
  __syncthreads();
  {
    int c = t;
    #pragma unroll
    for (int k8 = 0; k8 < 64; k8 += 8) {
      unsigned int p0 = (unsigned int)Wl[(k8 + 0) * 258 + c] | ((unsigned int)Wl[(k8 + 1) * 258 + c] << 16);
      unsigned int p1 = (unsigned int)Wl[(k8 + 2) * 258 + c] | ((unsigned int)Wl[(k8 + 3) * 258 + c] << 16);
      unsigned int p2 = (unsigned int)Wl[(k8 + 4) * 258 + c] | ((unsigned int)Wl[(k8 + 5) * 258 + c] << 16);
      unsigned int p3 = (unsigned int)Wl[(k8 + 6) * 258 + c] | ((unsigned int)Wl[(k8 + 7) * 258 + c] << 16);
      uint4 pk; pk.x = p0; pk.y = p1; pk.z = p2; pk.w = p3;
      *(uint4*)&WTx[c * 64 + k8] = pk;
    }
  }
  for (int idx = t; idx < 512; idx += 256) {
    int r = idx >> 6;
    int k = idx & 63;
    int h = r & 3;
    const void* av = (r >> 2) ? adst : asrc;
    float acc = 0.f;
    #pragma unroll 8
    for (int c = 0; c < 64; c++)
      acc += bf2f(Wl[k * 258 + h * 64 + c]) * loadF(av, h * 64 + c, f32);
    WTx[(256 + r) * 64 + k] = f2bf(acc);
  }
  for (int idx = t; idx < 512; idx += 256) WTx[264 * 64 + idx] = 0;
}

// ---------------- CSR build ----------------
__global__ __launch_bounds__(256) void hist_kernel(const void* __restrict__ ei, int E, int N,
                                                   const int* __restrict__ flags,
                                                   int* __restrict__ deg) {
  int e = blockIdx.x * 256 + threadIdx.x;
  if (e >= E) return;
  int is64 = flags[1];
  int d = edge_at(ei, (long long)E + e, is64);
  d = (d < 0 || d >= N) ? 0 : d;
  atomicAdd(&deg[d], 1);
}

__global__ __launch_bounds__(256) void partial_kernel(const int* __restrict__ deg,
                                                      int* __restrict__ blocksum, int N) {
  int t = threadIdx.x;
  int idx = blockIdx.x * 256 + t;
  int v = (idx < N) ? deg[idx] : 0;
  #pragma unroll
  for (int o = 1; o < 64; o <<= 1) v += __shfl_xor(v, o);
  __shared__ int ws[4];
  if ((t & 63) == 0) ws[t >> 6] = v;
  __syncthreads();
  if (t == 0) blocksum[blockIdx.x] = ws[0] + ws[1] + ws[2] + ws[3];
}

__global__ void scan_base_kernel(const int* __restrict__ blocksum,
                                 int* __restrict__ blockbase, int B) {
  int lane = threadIdx.x;
  int base = 0;
  if (lane == 0) blockbase[0] = 0;
  for (int start = 0; start < B; start += 64) {
    int idx = start + lane;
    int v = (idx < B) ? blocksum[idx] : 0;
    int sc = v;
    #pragma unroll
    for (int o = 1; o < 64; o <<= 1) {
      int u = __shfl_up(sc, o);
      if (lane >= o) sc += u;
    }
    if (idx < B) blockbase[idx + 1] = base + sc;
    base = __shfl(base + sc, 63);
  }
}

__global__ __launch_bounds__(256) void scan_final_kernel(const int* __restrict__ deg,
                                                         const int* __restrict__ blockbase,
                                                         int* __restrict__ offsets, int N) {
  int t = threadIdx.x;
  int lane = t & 63;
  int wid = t >> 6;
  int idx = blockIdx.x * 256 + t;
  int v = (idx < N) ? deg[idx] : 0;
  int sc = v;
  #pragma unroll
  for (int o = 1; o < 64; o <<= 1) {
    int u = __shfl_up(sc, o);
    if (lane >= o) sc += u;
  }
  __shared__ int ws[4];
  if (lane == 63) ws[wid] = sc;
  __syncthreads();
  int add = 0;
  #pragma unroll
  for (int w = 0; w < 4; w++) if (w < wid) add += ws[w];
  if (idx < N) offsets[idx + 1] = blockbase[blockIdx.x] + add + sc;
  if (idx == 0) offsets[0] = 0;
}

__global__ __launch_bounds__(256) void scatter_kernel(
    const void* __restrict__ ei, int E, int N, const int* __restrict__ flags,
    const int* __restrict__ offsets, int* __restrict__ cursor,
    int* __restrict__ csr_src) {
  int e = blockIdx.x * 256 + threadIdx.x;
  if (e >= E) return;
  int is64 = flags[1];
  int s = edge_at(ei, e, is64);
  int d = edge_at(ei, (long long)E + e, is64);
  s = (s < 0 || s >= N) ? 0 : s;
  d = (d < 0 || d >= N) ? 0 : d;
  int pos = offsets[d] + atomicAdd(&cursor[d], 1);
  csr_src[pos] = s;
}

// ---------------- MFMA GEMM: xh = x @ W (bf16) + als/ald tile; optional fused BN ----------------
// mode 0: x is layer input (dtype per flags[0]); mode 1: x is fp32 y, apply BN(gsum,gsq)+ReLU.
__global__ __launch_bounds__(256, 2) void gemm_mfma(
    const void* __restrict__ x, const unsigned short* __restrict__ WTx,
    const int* __restrict__ flags, int mode,
    const float* __restrict__ gsum, const float* __restrict__ gsq,
    const void* __restrict__ gamma, const void* __restrict__ beta,
    unsigned short* __restrict__ xh, float* __restrict__ als, float* __restrict__ ald,
    int N) {
  __shared__ unsigned short RP[4][16 * 264];  // per-wave repack tile
  __shared__ float bnsc[64], bnsh[64];
  int f32 = flags[0];
  int t = threadIdx.x;
  if (mode == 1) {
    if (t < 64) {
      float mu = gsum[t] / (float)N;
      float var = fmaxf(gsq[t] / (float)N - mu * mu, 0.f);
      float sc = loadF(gamma, t, f32) * rsqrtf(var + BN_EPS);
      bnsc[t] = sc;
      bnsh[t] = loadF(beta, t, f32) - mu * sc;
    }
    __syncthreads();
  }
  int wave = t >> 6, lane = t & 63;
  int q = lane >> 4, r16 = lane & 15;
  int m0 = blockIdx.x * 64 + wave * 16;
  if (m0 >= N) return;
  int row = m0 + r16;
  int rowc = row < N ? row : N - 1;

  bf16x8 a0, a1;
  if (mode == 1) {
    const float* xp = (const float*)x + (size_t)rowc * 64 + q * 8;
    float va[8], vb[8];
    *(float4*)&va[0] = ((const float4*)xp)[0];
    *(float4*)&va[4] = ((const float4*)xp)[1];
    *(float4*)&vb[0] = ((const float4*)(xp + 32))[0];
    *(float4*)&vb[4] = ((const float4*)(xp + 32))[1];
    int k0 = q * 8;
    #pragma unroll
    for (int jj = 0; jj < 8; jj++) {
      float v = fmaxf(va[jj] * bnsc[k0 + jj] + bnsh[k0 + jj], 0.f);
      float w = fmaxf(vb[jj] * bnsc[k0 + 32 + jj] + bnsh[k0 + 32 + jj], 0.f);
      a0[jj] = (short)f2bf(v);
      a1[jj] = (short)f2bf(w);
    }
  } else if (f32) {
    const float* xp = (const float*)x + (size_t)rowc * 64 + q * 8;
    float va[8], vb[8];
    *(float4*)&va[0] = ((const float4*)xp)[0];
    *(float4*)&va[4] = ((const float4*)xp)[1];
    *(float4*)&vb[0] = ((const float4*)(xp + 32))[0];
    *(float4*)&vb[4] = ((const float4*)(xp + 32))[1];
    #pragma unroll
    for (int jj = 0; jj < 8; jj++) {
      a0[jj] = (short)f2bf(va[jj]);
      a1[jj] = (short)f2bf(vb[jj]);
    }
  } else {
    const unsigned short* xp = (const unsigned short*)x + (size_t)rowc * 64 + q * 8;
    a0 = *(const bf16x8*)xp;
    a1 = *(const bf16x8*)(xp + 32);
  }

  f32x4 acc[17];
  #pragma unroll
  for (int tt = 0; tt < 17; tt++) acc[tt] = (f32x4){0.f, 0.f, 0.f, 0.f};
  #pragma unroll
  for (int tt = 0; tt < 17; tt++) {
    int c = tt * 16 + r16;
    bf16x8 b0 = *(const bf16x8*)(WTx + c * 64 + q * 8);
    bf16x8 b1 = *(const bf16x8*)(WTx + c * 64 + 32 + q * 8);
    acc[tt] = __builtin_amdgcn_mfma_f32_16x16x32_bf16(a0, b0, acc[tt], 0, 0, 0);
    acc[tt] = __builtin_amdgcn_mfma_f32_16x16x32_bf16(a1, b1, acc[tt], 0, 0, 0);
  }

  // epilogue 1: als/ald from tile 16
  {
    int obase = m0 + q * 4;
    #pragma unroll
    for (int rr = 0; rr < 4; rr++) {
      int orow = obase + rr;
      if (orow < N) {
        if (r16 < 4) als[orow * 4 + r16] = acc[16][rr];
        else if (r16 < 8) ald[orow * 4 + (r16 - 4)] = acc[16][rr];
      }
    }
  }
  // epilogue 2: repack via LDS, coalesced 16B stores
  unsigned short* rp = RP[wave];
  #pragma unroll
  for (int tt = 0; tt < 16; tt++) {
    #pragma unroll
    for (int rr = 0; rr < 4; rr++)
      rp[(q * 4 + rr) * 264 + tt * 16 + r16] = f2bf(acc[tt][rr]);
  }
  #pragma unroll
  for (int i = 0; i < 8; i++) {
    int g = i * 64 + lane;
    int r = g >> 5;
    int grp = g & 31;
    uint4 v = *(const uint4*)&rp[r * 264 + grp * 8];
    int orow = m0 + r;
    if (orow < N) ((uint4*)xh)[(size_t)orow * 32 + grp] = v;
  }
}

// ---------------- per-dst-node softmax aggregation + fused BN stats ----------------
// One wave per node (grid-strided). Lane covers channels 8*(lane&31).. (uint4 gather);
// half = lane>>5: half 0 = even edges + self, half 1 = odd edges.
__global__ __launch_bounds__(256) void agg_kernel(
    const unsigned short* __restrict__ xh,
    const float* __restrict__ als, const float* __restrict__ ald,
    const int* __restrict__ offsets, const int* __restrict__ csr_src,
    const void* __restrict__ bias, const int* __restrict__ flags,
    float* __restrict__ y, float* __restrict__ gsum, float* __restrict__ gsq, int N) {
  __shared__ float bsum[64], bsq[64];
  int t = threadIdx.x;
  if (t < 64) { bsum[t] = 0.f; bsq[t] = 0.f; }
  __syncthreads();
  int lane = t & 63;
  int wid = t >> 6;
  int hl = lane & 31;
  int h = hl >> 3;
  int half = lane >> 5;
  int f32 = flags[0];
  const uint4* xv = (const uint4*)xh;
  int stride = gridDim.x * 4;
  for (int n = blockIdx.x * 4 + wid; n < N; n += stride) {
    float ad = ald[n * 4 + h];
    float acc0 = 0.f, acc1 = 0.f, acc2 = 0.f, acc3 = 0.f;
    float acc4 = 0.f, acc5 = 0.f, acc6 = 0.f, acc7 = 0.f;
    float dsum = 0.f;
    if (half == 0) {  // implicit self loop
      float e = als[n * 4 + h] + ad;
      e = (e > 0.f) ? e : NEG_SLOPE * e;
      float p = __expf(e);
      dsum = p;
      uint4 v = xv[(size_t)n * 32 + hl];
      acc0 = p * asf(v.x << 16); acc1 = p * asf(v.x & 0xffff0000u);
      acc2 = p * asf(v.y << 16); acc3 = p * asf(v.y & 0xffff0000u);
      acc4 = p * asf(v.z << 16); acc5 = p * asf(v.z & 0xffff0000u);
      acc6 = p * asf(v.w << 16); acc7 = p * asf(v.w & 0xffff0000u);
    }
    int beg = offsets[n], end = offsets[n + 1];
    int imax = (end - beg + 1) >> 1;
    for (int i = 0; i < imax; i++) {
      int j = beg + 2 * i + half;
      if (j < end) {
        int s = csr_src[j];
        float e = als[s * 4 + h] + ad;
        e = (e > 0.f) ? e : NEG_SLOPE * e;
        float p = __expf(e);
        dsum += p;
        uint4 v = xv[(size_t)s * 32 + hl];
        acc0 += p * asf(v.x << 16); acc1 += p * asf(v.x & 0xffff0000u);
        acc2 += p * asf(v.y << 16); acc3 += p * asf(v.y & 0xffff0000u);
        acc4 += p * asf(v.z << 16); acc5 += p * asf(v.z & 0xffff0000u);
        acc6 += p * asf(v.w << 16); acc7 += p * asf(v.w & 0xffff0000u);
      }
    }
    // combine halves (even/odd edges)
    dsum += __shfl_xor(dsum, 32);
    acc0 += __shfl_xor(acc0, 32); acc1 += __shfl_xor(acc1, 32);
    acc2 += __shfl_xor(acc2, 32); acc3 += __shfl_xor(acc3, 32);
    acc4 += __shfl_xor(acc4, 32); acc5 += __shfl_xor(acc5, 32);
    acc6 += __shfl_xor(acc6, 32); acc7 += __shfl_xor(acc7, 32);
    float inv = 1.0f / dsum;
    acc0 *= inv; acc1 *= inv; acc2 *= inv; acc3 *= inv;
    acc4 *= inv; acc5 *= inv; acc6 *= inv; acc7 *= inv;
    // mean over heads: sum lanes {hl&7, +8, +16, +24}
    acc0 += __shfl_xor(acc0, 8); acc0 += __shfl_xor(acc0, 16);
    acc1 += __shfl_xor(acc1, 8); acc1 += __shfl_xor(acc1, 16);
    acc2 += __shfl_xor(acc2, 8); acc2 += __shfl_xor(acc2, 16);
    acc3 += __shfl_xor(acc3, 8); acc3 += __shfl_xor(acc3, 16);
    acc4 += __shfl_xor(acc4, 8); acc4 += __shfl_xor(acc4, 16);
    acc5 += __shfl_xor(acc5, 8); acc5 += __shfl_xor(acc5, 16);
    acc6 += __shfl_xor(acc6, 8); acc6 += __shfl_xor(acc6, 16);
    acc7 += __shfl_xor(acc7, 8); acc7 += __shfl_xor(acc7, 16);
    if (lane < 8) {
      int cb = 8 * lane;
      float o[8];
      o[0] = 0.25f * acc0 + loadF(bias, cb + 0, f32);
      o[1] = 0.25f * acc1 + loadF(bias, cb + 1, f32);
      o[2] = 0.25f * acc2 + loadF(bias, cb + 2, f32);
      o[3] = 0.25f * acc3 + loadF(bias, cb + 3, f32);
      o[4] = 0.25f * acc4 + loadF(bias, cb + 4, f32);
      o[5] = 0.25f * acc5 + loadF(bias, cb + 5, f32);
      o[6] = 0.25f * acc6 + loadF(bias, cb + 6, f32);
      o[7] = 0.25f * acc7 + loadF(bias, cb + 7, f32);
      float4 o0; o0.x = o[0]; o0.y = o[1]; o0.z = o[2]; o0.w = o[3];
      float4 o1; o1.x = o[4]; o1.y = o[5]; o1.z = o[6]; o1.w = o[7];
      *(float4*)(y + (size_t)n * 64 + cb) = o0;
      *(float4*)(y + (size_t)n * 64 + cb + 4) = o1;
      #pragma unroll
      for (int c = 0; c < 8; c++) {
        atomicAdd(&bsum[cb + c], o[c]);
        atomicAdd(&bsq[cb + c], o[c] * o[c]);
      }
    }
  }
  __syncthreads();
  if (t < 64) {
    atomicAdd(&gsum[t], bsum[t]);
    atomicAdd(&gsq[t], bsq[t]);
  }
}

// ---------------- BN apply + ReLU (final output only) ----------------
__global__ __launch_bounds__(256) void bn_kernel(
    const float* __restrict__ y, const float* __restrict__ gsum, const float* __restrict__ gsq,
    const void* __restrict__ gamma, const void* __restrict__ beta,
    const int* __restrict__ flags, float* __restrict__ out_f, int N) {
  int i = blockIdx.x * 256 + threadIdx.x;
  if (i >= N * 16) return;
  int f32 = flags[0];
  int cg = i & 15;
  float4 v = ((const float4*)y)[i];
  float4 s = ((const float4*)gsum)[cg];
  float4 q = ((const float4*)gsq)[cg];
  float inv_n = 1.0f / (float)N;
  float vv[4] = {v.x, v.y, v.z, v.w};
  float ss[4] = {s.x, s.y, s.z, s.w};
  float qq[4] = {q.x, q.y, q.z, q.w};
  float o[4];
  #pragma unroll
  for (int k = 0; k < 4; k++) {
    float g = loadF(gamma, 4 * cg + k, f32);
    float b = loadF(beta, 4 * cg + k, f32);
    float mu = ss[k] * inv_n;
    float var = fmaxf(qq[k] * inv_n - mu * mu, 0.f);
    float r = g * (vv[k] - mu) * rsqrtf(var + BN_EPS) + b;
    o[k] = r > 0.f ? r : 0.f;
  }
  float4 ov; ov.x = o[0]; ov.y = o[1]; ov.z = o[2]; ov.w = o[3];
  ((float4*)out_f)[i] = ov;
}

// ---------------- launch ----------------
extern "C" void kernel_launch(void* const* d_in, const int* in_sizes, int n_in,
                              void* d_out, int out_size, void* d_ws, size_t ws_size,
                              hipStream_t stream) {
  const void* x    = d_in[0];
  const void* ei   = d_in[1];
  const void* W0    = d_in[3];
  const void* asrc0 = d_in[4];
  const void* adst0 = d_in[5];
  const void* b0    = d_in[6];
  const void* g0    = d_in[7];
  const void* be0   = d_in[8];
  const void* W1    = d_in[9];
  const void* asrc1 = d_in[10];
  const void* adst1 = d_in[11];
  const void* b1    = d_in[12];
  const void* g1    = d_in[13];
  const void* be1   = d_in[14];

  int N = in_sizes[0] / 64;
  int E = in_sizes[1] / 2;
  int NB = (N + 255) / 256;   // scan blocks
  int NG = (N + 63) / 64;     // gemm blocks
  int NA = (N + 15) / 16;     // agg blocks: 4 nodes/block, 4 passes

  char* p = (char*)d_ws;
  auto alloc = [&](size_t bytes) -> char* {
    char* r = p;
    p += (bytes + 255) & ~(size_t)255;
    return r;
  };
  int* flags    = (int*)alloc(256);
  int* deg      = (int*)alloc((size_t)N * 4);
  int* cursor   = (int*)alloc((size_t)N * 4);
  int* offsets  = (int*)alloc((size_t)(N + 1) * 4);
  int* blocksum = (int*)alloc((size_t)NB * 4);
  int* blockbase= (int*)alloc((size_t)(NB + 1) * 4);
  int* csr_src  = (int*)alloc((size_t)E * 4);
  unsigned short* WTx0 = (unsigned short*)alloc(272 * 64 * 2);
  unsigned short* WTx1 = (unsigned short*)alloc(272 * 64 * 2);
  unsigned short* xh = (unsigned short*)alloc((size_t)N * 256 * 2);
  float* als    = (float*)alloc((size_t)N * 4 * 4);
  float* ald    = (float*)alloc((size_t)N * 4 * 4);
  float* y      = (float*)alloc((size_t)N * 64 * 4);
  float* gsum0  = (float*)alloc(256);
  float* gsq0   = (float*)alloc(256);
  float* gsum1  = (float*)alloc(256);
  float* gsq1   = (float*)alloc(256);

  hipMemsetAsync(deg, 0, (size_t)N * 4, stream);
  hipMemsetAsync(cursor, 0, (size_t)N * 4, stream);
  hipMemsetAsync(gsum0, 0, 1024, stream);  // gsum0..gsq1 contiguous

  detect_kernel<<<1, 256, 0, stream>>>((const unsigned short*)x, (const int*)ei, flags);
  wtrans_kernel<<<2, 256, 0, stream>>>(W0, asrc0, adst0, W1, asrc1, adst1, flags, WTx0, WTx1);

  hist_kernel<<<(E + 255) / 256, 256, 0, stream>>>(ei, E, N, flags, deg);
  partial_kernel<<<NB, 256, 0, stream>>>(deg, blocksum, N);
  scan_base_kernel<<<1, 64, 0, stream>>>(blocksum, blockbase, NB);
  scan_final_kernel<<<NB, 256, 0, stream>>>(deg, blockbase, offsets, N);
  scatter_kernel<<<(E + 255) / 256, 256, 0, stream>>>(ei, E, N, flags, offsets, cursor, csr_src);

  float* out_x = (float*)d_out;                    // output 0: final, fp32
  float* out_saved = out_x + (size_t)N * 64;       // output 1: layer-2 pre-BN, fp32

  // ---- layer 0 ----
  gemm_mfma<<<NG, 256, 0, stream>>>(x, WTx0, flags, 0, (const float*)nullptr,
                                    (const float*)nullptr, nullptr, nullptr,
                                    xh, als, ald, N);
  agg_kernel<<<NA, 256, 0, stream>>>(xh, als, ald, offsets, csr_src, b0, flags,
                                     y, gsum0, gsq0, N);
  // ---- layer 1 (BN of layer 0 fused into A-fragment load) ----
  gemm_mfma<<<NG, 256, 0, stream>>>(y, WTx1, flags, 1, gsum0, gsq0, g0, be0,
                                    xh, als, ald, N);
  agg_kernel<<<NA, 256, 0, stream>>>(xh, als, ald, offsets, csr_src, b1, flags,
                                     out_saved, gsum1, gsq1, N);
  bn_kernel<<<(N * 16 + 255) / 256, 256, 0, stream>>>(out_saved, gsum1, gsq1, g1, be1,
                                                      flags, out_x, N);
}

// Round 8
// 518.785 us; speedup vs baseline: 1.0188x; 1.0188x over previous
//
#include <hip/hip_runtime.h>
#include <stdint.h>

#define NEG_SLOPE 0.2f
#define BN_EPS 1e-5f

typedef __attribute__((ext_vector_type(8))) short bf16x8;
typedef __attribute__((ext_vector_type(4))) float f32x4;

// ---------------- bf16 helpers ----------------
__device__ __forceinline__ float bf2f(unsigned short u) {
  union { unsigned int i; float f; } v; v.i = ((unsigned int)u) << 16; return v.f;
}
__device__ __forceinline__ float asf(unsigned int u) {
  union { unsigned int i; float f; } v; v.i = u; return v.f;
}
__device__ __forceinline__ unsigned short f2bf(float f) {
  union { float f; unsigned int i; } v; v.f = f;
  unsigned int i = v.i;
  return (unsigned short)((i + 0x7fffu + ((i >> 16) & 1u)) >> 16);  // RNE
}
__device__ __forceinline__ float loadF(const void* p, long long i, int f32) {
  return f32 ? ((const float*)p)[i] : bf2f(((const unsigned short*)p)[i]);
}
__device__ __forceinline__ int edge_at(const void* ei, long long idx, int is64) {
  return is64 ? (int)((const long long*)ei)[idx] : ((const int*)ei)[idx];
}

// ---------------- input dtype detection ----------------
__global__ void detect_kernel(const unsigned short* __restrict__ x,
                              const int* __restrict__ ei32,
                              int* __restrict__ flags) {
  __shared__ int wild, oddnz;
  if (threadIdx.x == 0) { wild = 0; oddnz = 0; }
  __syncthreads();
  int lw = 0, lo = 0;
  for (int i = threadIdx.x; i < 4096; i += 256) {
    unsigned short u = x[i];
    int ex = (u >> 7) & 0xFF;
    if (ex >= 0x86) lw++;
    if (ei32[2 * i + 1] != 0) lo++;
  }
  if (lw) atomicAdd(&wild, lw);
  if (lo) atomicAdd(&oddnz, lo);
  __syncthreads();
  if (threadIdx.x == 0) { flags[0] = (wild > 64) ? 1 : 0; flags[1] = (oddnz == 0) ? 1 : 0; }
}

// ---------------- W preprocessing ----------------
// WTx [272 rows][64 k] bf16: rows 0..255 = W^T; 256..259 = Ws[h]; 260..263 = Wd[h]; 264..271 = 0.
__global__ __launch_bounds__(256) void wtrans_kernel(
    const void* __restrict__ W0, const void* __restrict__ as0, const void* __restrict__ ad0,
    const void* __restrict__ W1, const void* __restrict__ as1, const void* __restrict__ ad1,
    const int* __restrict__ flags,
    unsigned short* __restrict__ WTx0, unsigned short* __restrict__ WTx1) {
  const void* W = blockIdx.x ? W1 : W0;
  const void* asrc = blockIdx.x ? as1 : as0;
  const void* adst = blockIdx.x ? ad1 : ad0;
  unsigned short* WTx = blockIdx.x ? WTx1 : WTx0;
  int f32 = flags[0];
  __shared__ unsigned short Wl[64 * 258];
  int t = threadIdx.x;
  for (int i = t; i < 64 * 256; i += 256) {
    int k = i >> 8, c = i & 255;
    Wl[k * 258 + c] = f32 ? f2bf(((const float*)W)[i]) : ((const unsigned short*)W)[i];
  }
  __syncthreads();
  {
    int c = t;
    #pragma unroll
    for (int k8 = 0; k8 < 64; k8 += 8) {
      unsigned int p0 = (unsigned int)Wl[(k8 + 0) * 258 + c] | ((unsigned int)Wl[(k8 + 1) * 258 + c] << 16);
      unsigned int p1 = (unsigned int)Wl[(k8 + 2) * 258 + c] | ((unsigned int)Wl[(k8 + 3) * 258 + c] << 16);
      unsigned int p2 = (unsigned int)Wl[(k8 + 4) * 258 + c] | ((unsigned int)Wl[(k8 + 5) * 258 + c] << 16);
      unsigned int p3 = (unsigned int)Wl[(k8 + 6) * 258 + c] | ((unsigned int)Wl[(k8 + 7) * 258 + c] << 16);
      uint4 pk; pk.x = p0; pk.y = p1; pk.z = p2; pk.w = p3;
      *(uint4*)&WTx[c * 64 + k8] = pk;
    }
  }
  for (int idx = t; idx < 512; idx += 256) {
    int r = idx >> 6;
    int k = idx & 63;
    int h = r & 3;
    const void* av = (r >> 2) ? adst : asrc;
    float acc = 0.f;
    #pragma unroll 8
    for (int c = 0; c < 64; c++)
      acc += bf2f(Wl[k * 258 + h * 64 + c]) * loadF(av, h * 64 + c, f32);
    WTx[(256 + r) * 64 + k] = f2bf(acc);
  }
  for (int idx = t; idx < 512; idx += 256) WTx[264 * 64 + idx] = 0;
}

// ---------------- CSR build ----------------
__global__ __launch_bounds__(256) void hist_kernel(const void* __restrict__ ei, int E, int N,
                                                   const int* __restrict__ flags,
                                                   int* __restrict__ deg) {
  int e = blockIdx.x * 256 + threadIdx.x;
  if (e >= E) return;
  int is64 = flags[1];
  int d = edge_at(ei, (long long)E + e, is64);
  d = (d < 0 || d >= N) ? 0 : d;
  atomicAdd(&deg[d], 1);
}

__global__ __launch_bounds__(256) void partial_kernel(const int* __restrict__ deg,
                                                      int* __restrict__ blocksum, int N) {
  int t = threadIdx.x;
  int idx = blockIdx.x * 256 + t;
  int v = (idx < N) ? deg[idx] : 0;
  #pragma unroll
  for (int o = 1; o < 64; o <<= 1) v += __shfl_xor(v, o);
  __shared__ int ws[4];
  if ((t & 63) == 0) ws[t >> 6] = v;
  __syncthreads();
  if (t == 0) blocksum[blockIdx.x] = ws[0] + ws[1] + ws[2] + ws[3];
}

__global__ void scan_base_kernel(const int* __restrict__ blocksum,
                                 int* __restrict__ blockbase, int B) {
  int lane = threadIdx.x;
  int base = 0;
  if (lane == 0) blockbase[0] = 0;
  for (int start = 0; start < B; start += 64) {
    int idx = start + lane;
    int v = (idx < B) ? blocksum[idx] : 0;
    int sc = v;
    #pragma unroll
    for (int o = 1; o < 64; o <<= 1) {
      int u = __shfl_up(sc, o);
      if (lane >= o) sc += u;
    }
    if (idx < B) blockbase[idx + 1] = base + sc;
    base = __shfl(base + sc, 63);
  }
}

__global__ __launch_bounds__(256) void scan_final_kernel(const int* __restrict__ deg,
                                                         const int* __restrict__ blockbase,
                                                         int* __restrict__ offsets, int N) {
  int t = threadIdx.x;
  int lane = t & 63;
  int wid = t >> 6;
  int idx = blockIdx.x * 256 + t;
  int v = (idx < N) ? deg[idx] : 0;
  int sc = v;
  #pragma unroll
  for (int o = 1; o < 64; o <<= 1) {
    int u = __shfl_up(sc, o);
    if (lane >= o) sc += u;
  }
  __shared__ int ws[4];
  if (lane == 63) ws[wid] = sc;
  __syncthreads();
  int add = 0;
  #pragma unroll
  for (int w = 0; w < 4; w++) if (w < wid) add += ws[w];
  if (idx < N) offsets[idx + 1] = blockbase[blockIdx.x] + add + sc;
  if (idx == 0) offsets[0] = 0;
}

__global__ __launch_bounds__(256) void scatter_kernel(
    const void* __restrict__ ei, int E, int N, const int* __restrict__ flags,
    const int* __restrict__ offsets, int* __restrict__ cursor,
    int* __restrict__ csr_src) {
  int e = blockIdx.x * 256 + threadIdx.x;
  if (e >= E) return;
  int is64 = flags[1];
  int s = edge_at(ei, e, is64);
  int d = edge_at(ei, (long long)E + e, is64);
  s = (s < 0 || s >= N) ? 0 : s;
  d = (d < 0 || d >= N) ? 0 : d;
  int pos = offsets[d] + atomicAdd(&cursor[d], 1);
  csr_src[pos] = s;
}

// ---------------- MFMA GEMM: xh = x @ W (bf16) + als/ald tile; optional fused BN ----------------
// mode 0: x is layer input (dtype per flags[0]); mode 1: x is fp32 y, apply BN(gsum,gsq)+ReLU.
__global__ __launch_bounds__(256, 2) void gemm_mfma(
    const void* __restrict__ x, const unsigned short* __restrict__ WTx,
    const int* __restrict__ flags, int mode,
    const float* __restrict__ gsum, const float* __restrict__ gsq,
    const void* __restrict__ gamma, const void* __restrict__ beta,
    unsigned short* __restrict__ xh, float* __restrict__ als, float* __restrict__ ald,
    int N) {
  __shared__ unsigned short RP[4][16 * 264];
  __shared__ float bnsc[64], bnsh[64];
  int f32 = flags[0];
  int t = threadIdx.x;
  if (mode == 1) {
    if (t < 64) {
      float mu = gsum[t] / (float)N;
      float var = fmaxf(gsq[t] / (float)N - mu * mu, 0.f);
      float sc = loadF(gamma, t, f32) * rsqrtf(var + BN_EPS);
      bnsc[t] = sc;
      bnsh[t] = loadF(beta, t, f32) - mu * sc;
    }
    __syncthreads();
  }
  int wave = t >> 6, lane = t & 63;
  int q = lane >> 4, r16 = lane & 15;
  int m0 = blockIdx.x * 64 + wave * 16;
  if (m0 >= N) return;
  int row = m0 + r16;
  int rowc = row < N ? row : N - 1;

  bf16x8 a0, a1;
  if (mode == 1) {
    const float* xp = (const float*)x + (size_t)rowc * 64 + q * 8;
    float va[8], vb[8];
    *(float4*)&va[0] = ((const float4*)xp)[0];
    *(float4*)&va[4] = ((const float4*)xp)[1];
    *(float4*)&vb[0] = ((const float4*)(xp + 32))[0];
    *(float4*)&vb[4] = ((const float4*)(xp + 32))[1];
    int k0 = q * 8;
    #pragma unroll
    for (int jj = 0; jj < 8; jj++) {
      float v = fmaxf(va[jj] * bnsc[k0 + jj] + bnsh[k0 + jj], 0.f);
      float w = fmaxf(vb[jj] * bnsc[k0 + 32 + jj] + bnsh[k0 + 32 + jj], 0.f);
      a0[jj] = (short)f2bf(v);
      a1[jj] = (short)f2bf(w);
    }
  } else if (f32) {
    const float* xp = (const float*)x + (size_t)rowc * 64 + q * 8;
    float va[8], vb[8];
    *(float4*)&va[0] = ((const float4*)xp)[0];
    *(float4*)&va[4] = ((const float4*)xp)[1];
    *(float4*)&vb[0] = ((const float4*)(xp + 32))[0];
    *(float4*)&vb[4] = ((const float4*)(xp + 32))[1];
    #pragma unroll
    for (int jj = 0; jj < 8; jj++) {
      a0[jj] = (short)f2bf(va[jj]);
      a1[jj] = (short)f2bf(vb[jj]);
    }
  } else {
    const unsigned short* xp = (const unsigned short*)x + (size_t)rowc * 64 + q * 8;
    a0 = *(const bf16x8*)xp;
    a1 = *(const bf16x8*)(xp + 32);
  }

  f32x4 acc[17];
  #pragma unroll
  for (int tt = 0; tt < 17; tt++) acc[tt] = (f32x4){0.f, 0.f, 0.f, 0.f};
  #pragma unroll
  for (int tt = 0; tt < 17; tt++) {
    int c = tt * 16 + r16;
    bf16x8 b0 = *(const bf16x8*)(WTx + c * 64 + q * 8);
    bf16x8 b1 = *(const bf16x8*)(WTx + c * 64 + 32 + q * 8);
    acc[tt] = __builtin_amdgcn_mfma_f32_16x16x32_bf16(a0, b0, acc[tt], 0, 0, 0);
    acc[tt] = __builtin_amdgcn_mfma_f32_16x16x32_bf16(a1, b1, acc[tt], 0, 0, 0);
  }

  {
    int obase = m0 + q * 4;
    #pragma unroll
    for (int rr = 0; rr < 4; rr++) {
      int orow = obase + rr;
      if (orow < N) {
        if (r16 < 4) als[orow * 4 + r16] = acc[16][rr];
        else if (r16 < 8) ald[orow * 4 + (r16 - 4)] = acc[16][rr];
      }
    }
  }
  unsigned short* rp = RP[wave];
  #pragma unroll
  for (int tt = 0; tt < 16; tt++) {
    #pragma unroll
    for (int rr = 0; rr < 4; rr++)
      rp[(q * 4 + rr) * 264 + tt * 16 + r16] = f2bf(acc[tt][rr]);
  }
  #pragma unroll
  for (int i = 0; i < 8; i++) {
    int g = i * 64 + lane;
    int r = g >> 5;
    int grp = g & 31;
    uint4 v = *(const uint4*)&rp[r * 264 + grp * 8];
    int orow = m0 + r;
    if (orow < N) ((uint4*)xh)[(size_t)orow * 32 + grp] = v;
  }
}

// ---------------- per-dst-node softmax aggregation + fused BN stats ----------------
// One wave per node (grid-strided, 4 nodes/wave). Full wave per edge: lane -> channels
// 4*lane..4*lane+3 (head lane>>4), uint2 gather; 4-edge unroll for MLP=4.
__global__ __launch_bounds__(256) void agg_kernel(
    const unsigned short* __restrict__ xh,
    const float* __restrict__ als, const float* __restrict__ ald,
    const int* __restrict__ offsets, const int* __restrict__ csr_src,
    const void* __restrict__ bias, const int* __restrict__ flags,
    float* __restrict__ y, float* __restrict__ gsum, float* __restrict__ gsq, int N) {
  __shared__ float bsum[64], bsq[64];
  int t = threadIdx.x;
  if (t < 64) { bsum[t] = 0.f; bsq[t] = 0.f; }
  __syncthreads();
  int lane = t & 63;
  int wid = t >> 6;
  int h = lane >> 4;
  int f32 = flags[0];
  const uint2* xv = (const uint2*)xh;
  float rs0 = 0.f, rs1 = 0.f, rs2 = 0.f, rs3 = 0.f;  // BN partials (lanes 0..15)
  float rq0 = 0.f, rq1 = 0.f, rq2 = 0.f, rq3 = 0.f;
  int stride = gridDim.x * 4;
  for (int n = blockIdx.x * 4 + wid; n < N; n += stride) {
    float ad = ald[n * 4 + h];
    // implicit self loop
    float e = als[n * 4 + h] + ad;
    e = (e > 0.f) ? e : NEG_SLOPE * e;
    float p = __expf(e);
    float dsum = p;
    uint2 xs = xv[(size_t)n * 64 + lane];
    float a0 = p * asf(xs.x << 16), a1 = p * asf(xs.x & 0xffff0000u);
    float a2 = p * asf(xs.y << 16), a3 = p * asf(xs.y & 0xffff0000u);
    int beg = offsets[n], end = offsets[n + 1];
    int j = beg;
    for (; j + 4 <= end; j += 4) {
      int s0 = csr_src[j];
      int s1 = csr_src[j + 1];
      int s2 = csr_src[j + 2];
      int s3 = csr_src[j + 3];
      uint2 v0 = xv[(size_t)s0 * 64 + lane];
      uint2 v1 = xv[(size_t)s1 * 64 + lane];
      uint2 v2 = xv[(size_t)s2 * 64 + lane];
      uint2 v3 = xv[(size_t)s3 * 64 + lane];
      float e0 = als[s0 * 4 + h] + ad;
      float e1 = als[s1 * 4 + h] + ad;
      float e2 = als[s2 * 4 + h] + ad;
      float e3 = als[s3 * 4 + h] + ad;
      e0 = (e0 > 0.f) ? e0 : NEG_SLOPE * e0;
      e1 = (e1 > 0.f) ? e1 : NEG_SLOPE * e1;
      e2 = (e2 > 0.f) ? e2 : NEG_SLOPE * e2;
      e3 = (e3 > 0.f) ? e3 : NEG_SLOPE * e3;
      float p0 = __expf(e0);
      float p1 = __expf(e1);
      float p2 = __expf(e2);
      float p3 = __expf(e3);
      dsum += p0 + p1 + p2 + p3;
      a0 += p0 * asf(v0.x << 16) + p1 * asf(v1.x << 16)
          + p2 * asf(v2.x << 16) + p3 * asf(v3.x << 16);
      a1 += p0 * asf(v0.x & 0xffff0000u) + p1 * asf(v1.x & 0xffff0000u)
          + p2 * asf(v2.x & 0xffff0000u) + p3 * asf(v3.x & 0xffff0000u);
      a2 += p0 * asf(v0.y << 16) + p1 * asf(v1.y << 16)
          + p2 * asf(v2.y << 16) + p3 * asf(v3.y << 16);
      a3 += p0 * asf(v0.y & 0xffff0000u) + p1 * asf(v1.y & 0xffff0000u)
          + p2 * asf(v2.y & 0xffff0000u) + p3 * asf(v3.y & 0xffff0000u);
    }
    for (; j < end; j++) {
      int s0 = csr_src[j];
      uint2 v0 = xv[(size_t)s0 * 64 + lane];
      float e0 = als[s0 * 4 + h] + ad;
      e0 = (e0 > 0.f) ? e0 : NEG_SLOPE * e0;
      float p0 = __expf(e0);
      dsum += p0;
      a0 += p0 * asf(v0.x << 16);
      a1 += p0 * asf(v0.x & 0xffff0000u);
      a2 += p0 * asf(v0.y << 16);
      a3 += p0 * asf(v0.y & 0xffff0000u);
    }
    float inv = 1.0f / dsum;
    a0 *= inv; a1 *= inv; a2 *= inv; a3 *= inv;
    // mean over 4 heads: channel group lives in lanes {l, l+16, l+32, l+48}
    a0 += __shfl_xor(a0, 16); a0 += __shfl_xor(a0, 32);
    a1 += __shfl_xor(a1, 16); a1 += __shfl_xor(a1, 32);
    a2 += __shfl_xor(a2, 16); a2 += __shfl_xor(a2, 32);
    a3 += __shfl_xor(a3, 16); a3 += __shfl_xor(a3, 32);
    if (lane < 16) {
      float4 o;
      o.x = 0.25f * a0 + loadF(bias, 4 * lane + 0, f32);
      o.y = 0.25f * a1 + loadF(bias, 4 * lane + 1, f32);
      o.z = 0.25f * a2 + loadF(bias, 4 * lane + 2, f32);
      o.w = 0.25f * a3 + loadF(bias, 4 * lane + 3, f32);
      ((float4*)(y + (size_t)n * 64))[lane] = o;
      rs0 += o.x; rs1 += o.y; rs2 += o.z; rs3 += o.w;
      rq0 += o.x * o.x; rq1 += o.y * o.y; rq2 += o.z * o.z; rq3 += o.w * o.w;
    }
  }
  if (lane < 16) {
    atomicAdd(&bsum[4 * lane + 0], rs0);
    atomicAdd(&bsum[4 * lane + 1], rs1);
    atomicAdd(&bsum[4 * lane + 2], rs2);
    atomicAdd(&bsum[4 * lane + 3], rs3);
    atomicAdd(&bsq[4 * lane + 0], rq0);
    atomicAdd(&bsq[4 * lane + 1], rq1);
    atomicAdd(&bsq[4 * lane + 2], rq2);
    atomicAdd(&bsq[4 * lane + 3], rq3);
  }
  __syncthreads();
  if (t < 64) {
    atomicAdd(&gsum[t], bsum[t]);
    atomicAdd(&gsq[t], bsq[t]);
  }
}

// ---------------- BN apply + ReLU (final output only) ----------------
__global__ __launch_bounds__(256) void bn_kernel(
    const float* __restrict__ y, const float* __restrict__ gsum, const float* __restrict__ gsq,
    const void* __restrict__ gamma, const void* __restrict__ beta,
    const int* __restrict__ flags, float* __restrict__ out_f, int N) {
  int i = blockIdx.x * 256 + threadIdx.x;
  if (i >= N * 16) return;
  int f32 = flags[0];
  int cg = i & 15;
  float4 v = ((const float4*)y)[i];
  float4 s = ((const float4*)gsum)[cg];
  float4 q = ((const float4*)gsq)[cg];
  float inv_n = 1.0f / (float)N;
  float vv[4] = {v.x, v.y, v.z, v.w};
  float ss[4] = {s.x, s.y, s.z, s.w};
  float qq[4] = {q.x, q.y, q.z, q.w};
  float o[4];
  #pragma unroll
  for (int k = 0; k < 4; k++) {
    float g = loadF(gamma, 4 * cg + k, f32);
    float b = loadF(beta, 4 * cg + k, f32);
    float mu = ss[k] * inv_n;
    float var = fmaxf(qq[k] * inv_n - mu * mu, 0.f);
    float r = g * (vv[k] - mu) * rsqrtf(var + BN_EPS) + b;
    o[k] = r > 0.f ? r : 0.f;
  }
  float4 ov; ov.x = o[0]; ov.y = o[1]; ov.z = o[2]; ov.w = o[3];
  ((float4*)out_f)[i] = ov;
}

// ---------------- launch ----------------
extern "C" void kernel_launch(void* const* d_in, const int* in_sizes, int n_in,
                              void* d_out, int out_size, void* d_ws, size_t ws_size,
                              hipStream_t stream) {
  const void* x    = d_in[0];
  const void* ei   = d_in[1];
  const void* W0    = d_in[3];
  const void* asrc0 = d_in[4];
  const void* adst0 = d_in[5];
  const void* b0    = d_in[6];
  const void* g0    = d_in[7];
  const void* be0   = d_in[8];
  const void* W1    = d_in[9];
  const void* asrc1 = d_in[10];
  const void* adst1 = d_in[11];
  const void* b1    = d_in[12];
  const void* g1    = d_in[13];
  const void* be1   = d_in[14];

  int N = in_sizes[0] / 64;
  int E = in_sizes[1] / 2;
  int NB = (N + 255) / 256;   // scan blocks
  int NG = (N + 63) / 64;     // gemm blocks
  int NA = (N + 15) / 16;     // agg blocks: 4 waves/block, 4 nodes/wave

  char* p = (char*)d_ws;
  auto alloc = [&](size_t bytes) -> char* {
    char* r = p;
    p += (bytes + 255) & ~(size_t)255;
    return r;
  };
  int* flags    = (int*)alloc(256);
  int* deg      = (int*)alloc((size_t)N * 4);
  int* cursor   = (int*)alloc((size_t)N * 4);
  int* offsets  = (int*)alloc((size_t)(N + 1) * 4);
  int* blocksum = (int*)alloc((size_t)NB * 4);
  int* blockbase= (int*)alloc((size_t)(NB + 1) * 4);
  int* csr_src  = (int*)alloc((size_t)E * 4);
  unsigned short* WTx0 = (unsigned short*)alloc(272 * 64 * 2);
  unsigned short* WTx1 = (unsigned short*)alloc(272 * 64 * 2);
  unsigned short* xh = (unsigned short*)alloc((size_t)N * 256 * 2);
  float* als    = (float*)alloc((size_t)N * 4 * 4);
  float* ald    = (float*)alloc((size_t)N * 4 * 4);
  float* y      = (float*)alloc((size_t)N * 64 * 4);
  float* gsum0  = (float*)alloc(256);
  float* gsq0   = (float*)alloc(256);
  float* gsum1  = (float*)alloc(256);
  float* gsq1   = (float*)alloc(256);

  hipMemsetAsync(deg, 0, (size_t)N * 4, stream);
  hipMemsetAsync(cursor, 0, (size_t)N * 4, stream);
  hipMemsetAsync(gsum0, 0, 1024, stream);  // gsum0..gsq1 contiguous

  detect_kernel<<<1, 256, 0, stream>>>((const unsigned short*)x, (const int*)ei, flags);
  wtrans_kernel<<<2, 256, 0, stream>>>(W0, asrc0, adst0, W1, asrc1, adst1, flags, WTx0, WTx1);

  hist_kernel<<<(E + 255) / 256, 256, 0, stream>>>(ei, E, N, flags, deg);
  partial_kernel<<<NB, 256, 0, stream>>>(deg, blocksum, N);
  scan_base_kernel<<<1, 64, 0, stream>>>(blocksum, blockbase, NB);
  scan_final_kernel<<<NB, 256, 0, stream>>>(deg, blockbase, offsets, N);
  scatter_kernel<<<(E + 255) / 256, 256, 0, stream>>>(ei, E, N, flags, offsets, cursor, csr_src);

  float* out_x = (float*)d_out;                    // output 0: final, fp32
  float* out_saved = out_x + (size_t)N * 64;       // output 1: layer-2 pre-BN, fp32

  // ---- layer 0 ----
  gemm_mfma<<<NG, 256, 0, stream>>>(x, WTx0, flags, 0, (const float*)nullptr,
                                    (const float*)nullptr, nullptr, nullptr,
                                    xh, als, ald, N);
  agg_kernel<<<NA, 256, 0, stream>>>(xh, als, ald, offsets, csr_src, b0, flags,
                                     y, gsum0, gsq0, N);
  // ---- layer 1 (BN of layer 0 fused into A-fragment load) ----
  gemm_mfma<<<NG, 256, 0, stream>>>(y, WTx1, flags, 1, gsum0, gsq0, g0, be0,
                                    xh, als, ald, N);
  agg_kernel<<<NA, 256, 0, stream>>>(xh, als, ald, offsets, csr_src, b1, flags,
                                     out_saved, gsum1, gsq1, N);
  bn_kernel<<<(N * 16 + 255) / 256, 256, 0, stream>>>(out_saved, gsum1, gsq1, g1, be1,
                                                      flags, out_x, N);
}

// Round 9
// 457.873 us; speedup vs baseline: 1.1543x; 1.1330x over previous
//
#include <hip/hip_runtime.h>
#include <stdint.h>

#define NEG_SLOPE 0.2f
#define BN_EPS 1e-5f

typedef __attribute__((ext_vector_type(8))) short bf16x8;
typedef __attribute__((ext_vector_type(4))) float f32x4;

// ---------------- bf16 helpers ----------------
__device__ __forceinline__ float bf2f(unsigned short u) {
  union { unsigned int i; float f; } v; v.i = ((unsigned int)u) << 16; return v.f;
}
__device__ __forceinline__ float asf(unsigned int u) {
  union { unsigned int i; float f; } v; v.i = u; return v.f;
}
__device__ __forceinline__ unsigned short f2bf(float f) {
  union { float f; unsigned int i; } v; v.f = f;
  unsigned int i = v.i;
  return (unsigned short)((i + 0x7fffu + ((i >> 16) & 1u)) >> 16);  // RNE
}
__device__ __forceinline__ float loadF(const void* p, long long i, int f32) {
  return f32 ? ((const float*)p)[i] : bf2f(((const unsigned short*)p)[i]);
}
__device__ __forceinline__ int edge_at(const void* ei, long long idx, int is64) {
  return is64 ? (int)((const long long*)ei)[idx] : ((const int*)ei)[idx];
}

// ---------------- input dtype detection ----------------
__global__ void detect_kernel(const unsigned short* __restrict__ x,
                              const int* __restrict__ ei32,
                              int* __restrict__ flags) {
  __shared__ int wild, oddnz;
  if (threadIdx.x == 0) { wild = 0; oddnz = 0; }
  __syncthreads();
  int lw = 0, lo = 0;
  for (int i = threadIdx.x; i < 4096; i += 256) {
    unsigned short u = x[i];
    int ex = (u >> 7) & 0xFF;
    if (ex >= 0x86) lw++;
    if (ei32[2 * i + 1] != 0) lo++;
  }
  if (lw) atomicAdd(&wild, lw);
  if (lo) atomicAdd(&oddnz, lo);
  __syncthreads();
  if (threadIdx.x == 0) { flags[0] = (wild > 64) ? 1 : 0; flags[1] = (oddnz == 0) ? 1 : 0; }
}

// ---------------- W preprocessing ----------------
// WTx [272 rows][64 k] bf16: rows 0..255 = W^T; 256..259 = Ws[h]; 260..263 = Wd[h]; 264..271 = 0.
__global__ __launch_bounds__(256) void wtrans_kernel(
    const void* __restrict__ W0, const void* __restrict__ as0, const void* __restrict__ ad0,
    const void* __restrict__ W1, const void* __restrict__ as1, const void* __restrict__ ad1,
    const int* __restrict__ flags,
    unsigned short* __restrict__ WTx0, unsigned short* __restrict__ WTx1) {
  const void* W = blockIdx.x ? W1 : W0;
  const void* asrc = blockIdx.x ? as1 : as0;
  const void* adst = blockIdx.x ? ad1 : ad0;
  unsigned short* WTx = blockIdx.x ? WTx1 : WTx0;
  int f32 = flags[0];
  __shared__ unsigned short Wl[64 * 258];
  int t = threadIdx.x;
  for (int i = t; i < 64 * 256; i += 256) {
    int k = i >> 8, c = i & 255;
    Wl[k * 258 + c] = f32 ? f2bf(((const float*)W)[i]) : ((const unsigned short*)W)[i];
  }
  __syncthreads();
  {
    int c = t;
    #pragma unroll
    for (int k8 = 0; k8 < 64; k8 += 8) {
      unsigned int p0 = (unsigned int)Wl[(k8 + 0) * 258 + c] | ((unsigned int)Wl[(k8 + 1) * 258 + c] << 16);
      unsigned int p1 = (unsigned int)Wl[(k8 + 2) * 258 + c] | ((unsigned int)Wl[(k8 + 3) * 258 + c] << 16);
      unsigned int p2 = (unsigned int)Wl[(k8 + 4) * 258 + c] | ((unsigned int)Wl[(k8 + 5) * 258 + c] << 16);
      unsigned int p3 = (unsigned int)Wl[(k8 + 6) * 258 + c] | ((unsigned int)Wl[(k8 + 7) * 258 + c] << 16);
      uint4 pk; pk.x = p0; pk.y = p1; pk.z = p2; pk.w = p3;
      *(uint4*)&WTx[c * 64 + k8] = pk;
    }
  }
  for (int idx = t; idx < 512; idx += 256) {
    int r = idx >> 6;
    int k = idx & 63;
    int h = r & 3;
    const void* av = (r >> 2) ? adst : asrc;
    float acc = 0.f;
    #pragma unroll 8
    for (int c = 0; c < 64; c++)
      acc += bf2f(Wl[k * 258 + h * 64 + c]) * loadF(av, h * 64 + c, f32);
    WTx[(256 + r) * 64 + k] = f2bf(acc);
  }
  for (int idx = t; idx < 512; idx += 256) WTx[264 * 64 + idx] = 0;
}

// ---------------- CSR build ----------------
__global__ __launch_bounds__(256) void hist_kernel(const void* __restrict__ ei, int E, int N,
                                                   const int* __restrict__ flags,
                                                   int* __restrict__ deg) {
  int e = blockIdx.x * 256 + threadIdx.x;
  if (e >= E) return;
  int is64 = flags[1];
  int d = edge_at(ei, (long long)E + e, is64);
  d = (d < 0 || d >= N) ? 0 : d;
  atomicAdd(&deg[d], 1);
}

__global__ __launch_bounds__(256) void partial_kernel(const int* __restrict__ deg,
                                                      int* __restrict__ blocksum, int N) {
  int t = threadIdx.x;
  int idx = blockIdx.x * 256 + t;
  int v = (idx < N) ? deg[idx] : 0;
  #pragma unroll
  for (int o = 1; o < 64; o <<= 1) v += __shfl_xor(v, o);
  __shared__ int ws[4];
  if ((t & 63) == 0) ws[t >> 6] = v;
  __syncthreads();
  if (t == 0) blocksum[blockIdx.x] = ws[0] + ws[1] + ws[2] + ws[3];
}

__global__ void scan_base_kernel(const int* __restrict__ blocksum,
                                 int* __restrict__ blockbase, int B) {
  int lane = threadIdx.x;
  int base = 0;
  if (lane == 0) blockbase[0] = 0;
  for (int start = 0; start < B; start += 64) {
    int idx = start + lane;
    int v = (idx < B) ? blocksum[idx] : 0;
    int sc = v;
    #pragma unroll
    for (int o = 1; o < 64; o <<= 1) {
      int u = __shfl_up(sc, o);
      if (lane >= o) sc += u;
    }
    if (idx < B) blockbase[idx + 1] = base + sc;
    base = __shfl(base + sc, 63);
  }
}

__global__ __launch_bounds__(256) void scan_final_kernel(const int* __restrict__ deg,
                                                         const int* __restrict__ blockbase,
                                                         int* __restrict__ offsets, int N) {
  int t = threadIdx.x;
  int lane = t & 63;
  int wid = t >> 6;
  int idx = blockIdx.x * 256 + t;
  int v = (idx < N) ? deg[idx] : 0;
  int sc = v;
  #pragma unroll
  for (int o = 1; o < 64; o <<= 1) {
    int u = __shfl_up(sc, o);
    if (lane >= o) sc += u;
  }
  __shared__ int ws[4];
  if (lane == 63) ws[wid] = sc;
  __syncthreads();
  int add = 0;
  #pragma unroll
  for (int w = 0; w < 4; w++) if (w < wid) add += ws[w];
  if (idx < N) offsets[idx + 1] = blockbase[blockIdx.x] + add + sc;
  if (idx == 0) offsets[0] = 0;
}

__global__ __launch_bounds__(256) void scatter_kernel(
    const void* __restrict__ ei, int E, int N, const int* __restrict__ flags,
    const int* __restrict__ offsets, int* __restrict__ cursor,
    int* __restrict__ csr_src) {
  int e = blockIdx.x * 256 + threadIdx.x;
  if (e >= E) return;
  int is64 = flags[1];
  int s = edge_at(ei, e, is64);
  int d = edge_at(ei, (long long)E + e, is64);
  s = (s < 0 || s >= N) ? 0 : s;
  d = (d < 0 || d >= N) ? 0 : d;
  int pos = offsets[d] + atomicAdd(&cursor[d], 1);
  csr_src[pos] = s;
}

// ---------------- MFMA GEMM: xh = x @ W (bf16) + als/ald tile; optional fused BN ----------------
// mode 0: x is layer input (dtype per flags[0]); mode 1: x is fp32 y, apply BN(gsum,gsq)+ReLU.
// Chunked epilogue: 4-tile LDS buffer (8.7 KB) -> 3 blocks/CU.
__global__ __launch_bounds__(256, 3) void gemm_mfma(
    const void* __restrict__ x, const unsigned short* __restrict__ WTx,
    const int* __restrict__ flags, int mode,
    const float* __restrict__ gsum, const float* __restrict__ gsq,
    const void* __restrict__ gamma, const void* __restrict__ beta,
    unsigned short* __restrict__ xh, float* __restrict__ als, float* __restrict__ ald,
    int N) {
  __shared__ unsigned short RP[4][16 * 68];  // per-wave 4-tile repack chunk
  __shared__ float bnsc[64], bnsh[64];
  int f32 = flags[0];
  int t = threadIdx.x;
  if (mode == 1) {
    if (t < 64) {
      float mu = gsum[t] / (float)N;
      float var = fmaxf(gsq[t] / (float)N - mu * mu, 0.f);
      float sc = loadF(gamma, t, f32) * rsqrtf(var + BN_EPS);
      bnsc[t] = sc;
      bnsh[t] = loadF(beta, t, f32) - mu * sc;
    }
    __syncthreads();
  }
  int wave = t >> 6, lane = t & 63;
  int q = lane >> 4, r16 = lane & 15;
  int m0 = blockIdx.x * 64 + wave * 16;
  if (m0 >= N) return;
  int row = m0 + r16;
  int rowc = row < N ? row : N - 1;

  bf16x8 a0, a1;
  if (mode == 1) {
    const float* xp = (const float*)x + (size_t)rowc * 64 + q * 8;
    float va[8], vb[8];
    *(float4*)&va[0] = ((const float4*)xp)[0];
    *(float4*)&va[4] = ((const float4*)xp)[1];
    *(float4*)&vb[0] = ((const float4*)(xp + 32))[0];
    *(float4*)&vb[4] = ((const float4*)(xp + 32))[1];
    int k0 = q * 8;
    #pragma unroll
    for (int jj = 0; jj < 8; jj++) {
      float v = fmaxf(va[jj] * bnsc[k0 + jj] + bnsh[k0 + jj], 0.f);
      float w = fmaxf(vb[jj] * bnsc[k0 + 32 + jj] + bnsh[k0 + 32 + jj], 0.f);
      a0[jj] = (short)f2bf(v);
      a1[jj] = (short)f2bf(w);
    }
  } else if (f32) {
    const float* xp = (const float*)x + (size_t)rowc * 64 + q * 8;
    float va[8], vb[8];
    *(float4*)&va[0] = ((const float4*)xp)[0];
    *(float4*)&va[4] = ((const float4*)xp)[1];
    *(float4*)&vb[0] = ((const float4*)(xp + 32))[0];
    *(float4*)&vb[4] = ((const float4*)(xp + 32))[1];
    #pragma unroll
    for (int jj = 0; jj < 8; jj++) {
      a0[jj] = (short)f2bf(va[jj]);
      a1[jj] = (short)f2bf(vb[jj]);
    }
  } else {
    const unsigned short* xp = (const unsigned short*)x + (size_t)rowc * 64 + q * 8;
    a0 = *(const bf16x8*)xp;
    a1 = *(const bf16x8*)(xp + 32);
  }

  f32x4 acc[17];
  #pragma unroll
  for (int tt = 0; tt < 17; tt++) acc[tt] = (f32x4){0.f, 0.f, 0.f, 0.f};
  #pragma unroll
  for (int tt = 0; tt < 17; tt++) {
    int c = tt * 16 + r16;
    bf16x8 b0 = *(const bf16x8*)(WTx + c * 64 + q * 8);
    bf16x8 b1 = *(const bf16x8*)(WTx + c * 64 + 32 + q * 8);
    acc[tt] = __builtin_amdgcn_mfma_f32_16x16x32_bf16(a0, b0, acc[tt], 0, 0, 0);
    acc[tt] = __builtin_amdgcn_mfma_f32_16x16x32_bf16(a1, b1, acc[tt], 0, 0, 0);
  }

  // epilogue 1: als/ald from tile 16
  {
    int obase = m0 + q * 4;
    #pragma unroll
    for (int rr = 0; rr < 4; rr++) {
      int orow = obase + rr;
      if (orow < N) {
        if (r16 < 4) als[orow * 4 + r16] = acc[16][rr];
        else if (r16 < 8) ald[orow * 4 + (r16 - 4)] = acc[16][rr];
      }
    }
  }
  // epilogue 2: 4 chunked passes, per-wave LDS repack (wave-internal, no barrier)
  unsigned short* rp = RP[wave];
  #pragma unroll
  for (int g4 = 0; g4 < 4; g4++) {
    #pragma unroll
    for (int tt2 = 0; tt2 < 4; tt2++) {
      int tile = g4 * 4 + tt2;
      #pragma unroll
      for (int rr = 0; rr < 4; rr++)
        rp[(q * 4 + rr) * 68 + tt2 * 16 + r16] = f2bf(acc[tile][rr]);
    }
    #pragma unroll
    for (int i = 0; i < 2; i++) {
      int g = i * 64 + lane;
      int r = g >> 3;          // row 0..15
      int grp = g & 7;         // uint4 group within 64-col chunk
      uint4 v = *(const uint4*)&rp[r * 68 + grp * 8];
      int orow = m0 + r;
      if (orow < N) ((uint4*)xh)[(size_t)orow * 32 + g4 * 8 + grp] = v;
    }
  }
}

// ---------------- per-dst-node softmax aggregation (r6-proven frame) ----------------
// One node per wave; lane -> channels 4*lane.. (head lane>>4); 2-edge unroll.
__global__ __launch_bounds__(256) void agg_kernel(
    const unsigned short* __restrict__ xh,
    const float* __restrict__ als, const float* __restrict__ ald,
    const int* __restrict__ offsets, const int* __restrict__ csr_src,
    const void* __restrict__ bias, const int* __restrict__ flags,
    float* __restrict__ y, int N) {
  int lane = threadIdx.x & 63;
  int wid = threadIdx.x >> 6;
  int n = blockIdx.x * 4 + wid;
  if (n >= N) return;
  int h = lane >> 4;
  const uint2* xv = (const uint2*)xh;
  float ad = ald[n * 4 + h];
  float e = als[n * 4 + h] + ad;  // implicit self loop
  e = (e > 0.f) ? e : NEG_SLOPE * e;
  float p = __expf(e);
  float dsum = p;
  uint2 xs = xv[(size_t)n * 64 + lane];
  float a0 = p * asf(xs.x << 16), a1 = p * asf(xs.x & 0xffff0000u);
  float a2 = p * asf(xs.y << 16), a3 = p * asf(xs.y & 0xffff0000u);
  int beg = offsets[n], end = offsets[n + 1];
  int j = beg;
  for (; j + 2 <= end; j += 2) {
    int s0 = csr_src[j];
    int s1 = csr_src[j + 1];
    uint2 v0 = xv[(size_t)s0 * 64 + lane];
    uint2 v1 = xv[(size_t)s1 * 64 + lane];
    float e0 = als[s0 * 4 + h] + ad;
    float e1 = als[s1 * 4 + h] + ad;
    e0 = (e0 > 0.f) ? e0 : NEG_SLOPE * e0;
    e1 = (e1 > 0.f) ? e1 : NEG_SLOPE * e1;
    float p0 = __expf(e0);
    float p1 = __expf(e1);
    dsum += p0 + p1;
    a0 += p0 * asf(v0.x << 16) + p1 * asf(v1.x << 16);
    a1 += p0 * asf(v0.x & 0xffff0000u) + p1 * asf(v1.x & 0xffff0000u);
    a2 += p0 * asf(v0.y << 16) + p1 * asf(v1.y << 16);
    a3 += p0 * asf(v0.y & 0xffff0000u) + p1 * asf(v1.y & 0xffff0000u);
  }
  if (j < end) {
    int s0 = csr_src[j];
    uint2 v0 = xv[(size_t)s0 * 64 + lane];
    float e0 = als[s0 * 4 + h] + ad;
    e0 = (e0 > 0.f) ? e0 : NEG_SLOPE * e0;
    float p0 = __expf(e0);
    dsum += p0;
    a0 += p0 * asf(v0.x << 16);
    a1 += p0 * asf(v0.x & 0xffff0000u);
    a2 += p0 * asf(v0.y << 16);
    a3 += p0 * asf(v0.y & 0xffff0000u);
  }
  float inv = 1.0f / dsum;
  a0 *= inv; a1 *= inv; a2 *= inv; a3 *= inv;
  // mean over 4 heads
  a0 += __shfl_xor(a0, 16); a0 += __shfl_xor(a0, 32);
  a1 += __shfl_xor(a1, 16); a1 += __shfl_xor(a1, 32);
  a2 += __shfl_xor(a2, 16); a2 += __shfl_xor(a2, 32);
  a3 += __shfl_xor(a3, 16); a3 += __shfl_xor(a3, 32);
  if (lane < 16) {
    int f32 = flags[0];
    float4 o;
    o.x = 0.25f * a0 + loadF(bias, 4 * lane + 0, f32);
    o.y = 0.25f * a1 + loadF(bias, 4 * lane + 1, f32);
    o.z = 0.25f * a2 + loadF(bias, 4 * lane + 2, f32);
    o.w = 0.25f * a3 + loadF(bias, 4 * lane + 3, f32);
    ((float4*)(y + (size_t)n * 64))[lane] = o;
  }
}

// ---------------- BN stats (per-channel sum / sumsq) ----------------
__global__ __launch_bounds__(256) void stats_kernel(const float* __restrict__ y,
                                                    float* __restrict__ gsum,
                                                    float* __restrict__ gsq, int N) {
  __shared__ float ls[256], lq[256];
  int t = threadIdx.x;
  int c = t & 63;
  int r0 = blockIdx.x * 4 + (t >> 6);
  float s = 0.f, q = 0.f;
  for (int r = r0; r < N; r += gridDim.x * 4) {
    float v = y[(size_t)r * 64 + c];
    s += v; q += v * v;
  }
  ls[t] = s; lq[t] = q;
  __syncthreads();
  if (t < 64) {
    s = ls[t] + ls[t + 64] + ls[t + 128] + ls[t + 192];
    q = lq[t] + lq[t + 64] + lq[t + 128] + lq[t + 192];
    atomicAdd(&gsum[c], s);
    atomicAdd(&gsq[c], q);
  }
}

// ---------------- BN apply + ReLU (final output only) ----------------
__global__ __launch_bounds__(256) void bn_kernel(
    const float* __restrict__ y, const float* __restrict__ gsum, const float* __restrict__ gsq,
    const void* __restrict__ gamma, const void* __restrict__ beta,
    const int* __restrict__ flags, float* __restrict__ out_f, int N) {
  int i = blockIdx.x * 256 + threadIdx.x;
  if (i >= N * 16) return;
  int f32 = flags[0];
  int cg = i & 15;
  float4 v = ((const float4*)y)[i];
  float4 s = ((const float4*)gsum)[cg];
  float4 q = ((const float4*)gsq)[cg];
  float inv_n = 1.0f / (float)N;
  float vv[4] = {v.x, v.y, v.z, v.w};
  float ss[4] = {s.x, s.y, s.z, s.w};
  float qq[4] = {q.x, q.y, q.z, q.w};
  float o[4];
  #pragma unroll
  for (int k = 0; k < 4; k++) {
    float g = loadF(gamma, 4 * cg + k, f32);
    float b = loadF(beta, 4 * cg + k, f32);
    float mu = ss[k] * inv_n;
    float var = fmaxf(qq[k] * inv_n - mu * mu, 0.f);
    float r = g * (vv[k] - mu) * rsqrtf(var + BN_EPS) + b;
    o[k] = r > 0.f ? r : 0.f;
  }
  float4 ov; ov.x = o[0]; ov.y = o[1]; ov.z = o[2]; ov.w = o[3];
  ((float4*)out_f)[i] = ov;
}

// ---------------- launch ----------------
extern "C" void kernel_launch(void* const* d_in, const int* in_sizes, int n_in,
                              void* d_out, int out_size, void* d_ws, size_t ws_size,
                              hipStream_t stream) {
  const void* x    = d_in[0];
  const void* ei   = d_in[1];
  const void* W0    = d_in[3];
  const void* asrc0 = d_in[4];
  const void* adst0 = d_in[5];
  const void* b0    = d_in[6];
  const void* g0    = d_in[7];
  const void* be0   = d_in[8];
  const void* W1    = d_in[9];
  const void* asrc1 = d_in[10];
  const void* adst1 = d_in[11];
  const void* b1    = d_in[12];
  const void* g1    = d_in[13];
  const void* be1   = d_in[14];

  int N = in_sizes[0] / 64;
  int E = in_sizes[1] / 2;
  int NB = (N + 255) / 256;   // scan blocks
  int NG = (N + 63) / 64;     // gemm blocks
  int NA = (N + 3) / 4;       // agg blocks: one node per wave

  char* p = (char*)d_ws;
  auto alloc = [&](size_t bytes) -> char* {
    char* r = p;
    p += (bytes + 255) & ~(size_t)255;
    return r;
  };
  int* flags    = (int*)alloc(256);
  int* deg      = (int*)alloc((size_t)N * 4);
  int* cursor   = (int*)alloc((size_t)N * 4);
  int* offsets  = (int*)alloc((size_t)(N + 1) * 4);
  int* blocksum = (int*)alloc((size_t)NB * 4);
  int* blockbase= (int*)alloc((size_t)(NB + 1) * 4);
  int* csr_src  = (int*)alloc((size_t)E * 4);
  unsigned short* WTx0 = (unsigned short*)alloc(272 * 64 * 2);
  unsigned short* WTx1 = (unsigned short*)alloc(272 * 64 * 2);
  unsigned short* xh = (unsigned short*)alloc((size_t)N * 256 * 2);
  float* als    = (float*)alloc((size_t)N * 4 * 4);
  float* ald    = (float*)alloc((size_t)N * 4 * 4);
  float* y      = (float*)alloc((size_t)N * 64 * 4);
  float* gsum0  = (float*)alloc(256);
  float* gsq0   = (float*)alloc(256);
  float* gsum1  = (float*)alloc(256);
  float* gsq1   = (float*)alloc(256);

  hipMemsetAsync(deg, 0, (size_t)N * 4, stream);
  hipMemsetAsync(cursor, 0, (size_t)N * 4, stream);
  hipMemsetAsync(gsum0, 0, 1024, stream);  // gsum0..gsq1 contiguous

  detect_kernel<<<1, 256, 0, stream>>>((const unsigned short*)x, (const int*)ei, flags);
  wtrans_kernel<<<2, 256, 0, stream>>>(W0, asrc0, adst0, W1, asrc1, adst1, flags, WTx0, WTx1);

  hist_kernel<<<(E + 255) / 256, 256, 0, stream>>>(ei, E, N, flags, deg);
  partial_kernel<<<NB, 256, 0, stream>>>(deg, blocksum, N);
  scan_base_kernel<<<1, 64, 0, stream>>>(blocksum, blockbase, NB);
  scan_final_kernel<<<NB, 256, 0, stream>>>(deg, blockbase, offsets, N);
  scatter_kernel<<<(E + 255) / 256, 256, 0, stream>>>(ei, E, N, flags, offsets, cursor, csr_src);

  float* out_x = (float*)d_out;                    // output 0: final, fp32
  float* out_saved = out_x + (size_t)N * 64;       // output 1: layer-2 pre-BN, fp32

  // ---- layer 0 ----
  gemm_mfma<<<NG, 256, 0, stream>>>(x, WTx0, flags, 0, (const float*)nullptr,
                                    (const float*)nullptr, nullptr, nullptr,
                                    xh, als, ald, N);
  agg_kernel<<<NA, 256, 0, stream>>>(xh, als, ald, offsets, csr_src, b0, flags, y, N);
  stats_kernel<<<250, 256, 0, stream>>>(y, gsum0, gsq0, N);
  // ---- layer 1 (BN of layer 0 fused into gemm A-load) ----
  gemm_mfma<<<NG, 256, 0, stream>>>(y, WTx1, flags, 1, gsum0, gsq0, g0, be0,
                                    xh, als, ald, N);
  agg_kernel<<<NA, 256, 0, stream>>>(xh, als, ald, offsets, csr_src, b1, flags, out_saved, N);
  stats_kernel<<<250, 256, 0, stream>>>(out_saved, gsum1, gsq1, N);
  bn_kernel<<<(N * 16 + 255) / 256, 256, 0, stream>>>(out_saved, gsum1, gsq1, g1, be1,
                                                      flags, out_x, N);
}

// Round 10
// 428.509 us; speedup vs baseline: 1.2334x; 1.0685x over previous
//
#include <hip/hip_runtime.h>
#include <stdint.h>

#define NEG_SLOPE 0.2f
#define BN_EPS 1e-5f

typedef __attribute__((ext_vector_type(8))) short bf16x8;
typedef __attribute__((ext_vector_type(4))) float f32x4;

// ---------------- bf16 helpers ----------------
__device__ __forceinline__ float bf2f(unsigned short u) {
  union { unsigned int i; float f; } v; v.i = ((unsigned int)u) << 16; return v.f;
}
__device__ __forceinline__ float asf(unsigned int u) {
  union { unsigned int i; float f; } v; v.i = u; return v.f;
}
__device__ __forceinline__ unsigned short f2bf(float f) {
  union { float f; unsigned int i; } v; v.f = f;
  unsigned int i = v.i;
  return (unsigned short)((i + 0x7fffu + ((i >> 16) & 1u)) >> 16);  // RNE
}
__device__ __forceinline__ float loadF(const void* p, long long i, int f32) {
  return f32 ? ((const float*)p)[i] : bf2f(((const unsigned short*)p)[i]);
}
__device__ __forceinline__ int edge_at(const void* ei, long long idx, int is64) {
  return is64 ? (int)((const long long*)ei)[idx] : ((const int*)ei)[idx];
}

// ---------------- input dtype detection ----------------
__global__ void detect_kernel(const unsigned short* __restrict__ x,
                              const int* __restrict__ ei32,
                              int* __restrict__ flags) {
  __shared__ int wild, oddnz;
  if (threadIdx.x == 0) { wild = 0; oddnz = 0; }
  __syncthreads();
  int lw = 0, lo = 0;
  for (int i = threadIdx.x; i < 4096; i += 256) {
    unsigned short u = x[i];
    int ex = (u >> 7) & 0xFF;
    if (ex >= 0x86) lw++;
    if (ei32[2 * i + 1] != 0) lo++;
  }
  if (lw) atomicAdd(&wild, lw);
  if (lo) atomicAdd(&oddnz, lo);
  __syncthreads();
  if (threadIdx.x == 0) { flags[0] = (wild > 64) ? 1 : 0; flags[1] = (oddnz == 0) ? 1 : 0; }
}

// ---------------- W preprocessing ----------------
// WTx [272 rows][64 k] bf16: rows 0..255 = W^T; 256..259 = Ws[h]; 260..263 = Wd[h]; 264..271 = 0.
__global__ __launch_bounds__(256) void wtrans_kernel(
    const void* __restrict__ W0, const void* __restrict__ as0, const void* __restrict__ ad0,
    const void* __restrict__ W1, const void* __restrict__ as1, const void* __restrict__ ad1,
    const int* __restrict__ flags,
    unsigned short* __restrict__ WTx0, unsigned short* __restrict__ WTx1) {
  const void* W = blockIdx.x ? W1 : W0;
  const void* asrc = blockIdx.x ? as1 : as0;
  const void* adst = blockIdx.x ? ad1 : ad0;
  unsigned short* WTx = blockIdx.x ? WTx1 : WTx0;
  int f32 = flags[0];
  __shared__ unsigned short Wl[64 * 258];
  int t = threadIdx.x;
  for (int i = t; i < 64 * 256; i += 256) {
    int k = i >> 8, c = i & 255;
    Wl[k * 258 + c] = f32 ? f2bf(((const float*)W)[i]) : ((const unsigned short*)W)[i];
  }
  __syncthreads();
  {
    int c = t;
    #pragma unroll
    for (int k8 = 0; k8 < 64; k8 += 8) {
      unsigned int p0 = (unsigned int)Wl[(k8 + 0) * 258 + c] | ((unsigned int)Wl[(k8 + 1) * 258 + c] << 16);
      unsigned int p1 = (unsigned int)Wl[(k8 + 2) * 258 + c] | ((unsigned int)Wl[(k8 + 3) * 258 + c] << 16);
      unsigned int p2 = (unsigned int)Wl[(k8 + 4) * 258 + c] | ((unsigned int)Wl[(k8 + 5) * 258 + c] << 16);
      unsigned int p3 = (unsigned int)Wl[(k8 + 6) * 258 + c] | ((unsigned int)Wl[(k8 + 7) * 258 + c] << 16);
      uint4 pk; pk.x = p0; pk.y = p1; pk.z = p2; pk.w = p3;
      *(uint4*)&WTx[c * 64 + k8] = pk;
    }
  }
  for (int idx = t; idx < 512; idx += 256) {
    int r = idx >> 6;
    int k = idx & 63;
    int h = r & 3;
    const void* av = (r >> 2) ? adst : asrc;
    float acc = 0.f;
    #pragma unroll 8
    for (int c = 0; c < 64; c++)
      acc += bf2f(Wl[k * 258 + h * 64 + c]) * loadF(av, h * 64 + c, f32);
    WTx[(256 + r) * 64 + k] = f2bf(acc);
  }
  for (int idx = t; idx < 512; idx += 256) WTx[264 * 64 + idx] = 0;
}

// ---------------- CSR build ----------------
__global__ __launch_bounds__(256) void hist_kernel(const void* __restrict__ ei, int E, int N,
                                                   const int* __restrict__ flags,
                                                   int* __restrict__ deg) {
  int e = blockIdx.x * 256 + threadIdx.x;
  if (e >= E) return;
  int is64 = flags[1];
  int d = edge_at(ei, (long long)E + e, is64);
  d = (d < 0 || d >= N) ? 0 : d;
  atomicAdd(&deg[d], 1);
}

__global__ __launch_bounds__(256) void partial_kernel(const int* __restrict__ deg,
                                                      int* __restrict__ blocksum, int N) {
  int t = threadIdx.x;
  int idx = blockIdx.x * 256 + t;
  int v = (idx < N) ? deg[idx] : 0;
  #pragma unroll
  for (int o = 1; o < 64; o <<= 1) v += __shfl_xor(v, o);
  __shared__ int ws[4];
  if ((t & 63) == 0) ws[t >> 6] = v;
  __syncthreads();
  if (t == 0) blocksum[blockIdx.x] = ws[0] + ws[1] + ws[2] + ws[3];
}

__global__ void scan_base_kernel(const int* __restrict__ blocksum,
                                 int* __restrict__ blockbase, int B) {
  int lane = threadIdx.x;
  int base = 0;
  if (lane == 0) blockbase[0] = 0;
  for (int start = 0; start < B; start += 64) {
    int idx = start + lane;
    int v = (idx < B) ? blocksum[idx] : 0;
    int sc = v;
    #pragma unroll
    for (int o = 1; o < 64; o <<= 1) {
      int u = __shfl_up(sc, o);
      if (lane >= o) sc += u;
    }
    if (idx < B) blockbase[idx + 1] = base + sc;
    base = __shfl(base + sc, 63);
  }
}

__global__ __launch_bounds__(256) void scan_final_kernel(const int* __restrict__ deg,
                                                         const int* __restrict__ blockbase,
                                                         int* __restrict__ offsets, int N) {
  int t = threadIdx.x;
  int lane = t & 63;
  int wid = t >> 6;
  int idx = blockIdx.x * 256 + t;
  int v = (idx < N) ? deg[idx] : 0;
  int sc = v;
  #pragma unroll
  for (int o = 1; o < 64; o <<= 1) {
    int u = __shfl_up(sc, o);
    if (lane >= o) sc += u;
  }
  __shared__ int ws[4];
  if (lane == 63) ws[wid] = sc;
  __syncthreads();
  int add = 0;
  #pragma unroll
  for (int w = 0; w < 4; w++) if (w < wid) add += ws[w];
  if (idx < N) offsets[idx + 1] = blockbase[blockIdx.x] + add + sc;
  if (idx == 0) offsets[0] = 0;
}

__global__ __launch_bounds__(256) void scatter_kernel(
    const void* __restrict__ ei, int E, int N, const int* __restrict__ flags,
    const int* __restrict__ offsets, int* __restrict__ cursor,
    int* __restrict__ csr_src) {
  int e = blockIdx.x * 256 + threadIdx.x;
  if (e >= E) return;
  int is64 = flags[1];
  int s = edge_at(ei, e, is64);
  int d = edge_at(ei, (long long)E + e, is64);
  s = (s < 0 || s >= N) ? 0 : s;
  d = (d < 0 || d >= N) ? 0 : d;
  int pos = offsets[d] + atomicAdd(&cursor[d], 1);
  csr_src[pos] = s;
}

// ---------------- MFMA GEMM: xh = x @ W (bf16) + als/ald tile; optional fused BN ----------------
// mode 0: x is layer input (dtype per flags[0]); mode 1: x is fp32 y, apply BN(gsum,gsq)+ReLU.
// WTx staged into LDS (padded stride 68 -> 2-way banks, free); chunked repack epilogue.
__global__ __launch_bounds__(256, 3) void gemm_mfma(
    const void* __restrict__ x, const unsigned short* __restrict__ WTx,
    const int* __restrict__ flags, int mode,
    const float* __restrict__ gsum, const float* __restrict__ gsq,
    const void* __restrict__ gamma, const void* __restrict__ beta,
    unsigned short* __restrict__ xh, float* __restrict__ als, float* __restrict__ ald,
    int N) {
  __shared__ unsigned short WTs[272 * 68];    // 36 KB staged weights
  __shared__ unsigned short RP[4][16 * 68];   // per-wave repack chunk (8.5 KB)
  __shared__ float bnsc[64], bnsh[64];
  int f32 = flags[0];
  int t = threadIdx.x;
  // stage WTx -> LDS (2176 uint4 groups, coalesced)
  for (int i = t; i < 272 * 8; i += 256) {
    int c = i >> 3, g = i & 7;
    uint4 v = ((const uint4*)WTx)[i];
    *(uint4*)&WTs[c * 68 + g * 8] = v;
  }
  if (mode == 1 && t < 64) {
    float mu = gsum[t] / (float)N;
    float var = fmaxf(gsq[t] / (float)N - mu * mu, 0.f);
    float sc = loadF(gamma, t, f32) * rsqrtf(var + BN_EPS);
    bnsc[t] = sc;
    bnsh[t] = loadF(beta, t, f32) - mu * sc;
  }
  __syncthreads();

  int wave = t >> 6, lane = t & 63;
  int q = lane >> 4, r16 = lane & 15;
  int m0 = blockIdx.x * 64 + wave * 16;
  if (m0 >= N) return;
  int row = m0 + r16;
  int rowc = row < N ? row : N - 1;

  bf16x8 a0, a1;
  if (mode == 1) {
    const float* xp = (const float*)x + (size_t)rowc * 64 + q * 8;
    float va[8], vb[8];
    *(float4*)&va[0] = ((const float4*)xp)[0];
    *(float4*)&va[4] = ((const float4*)xp)[1];
    *(float4*)&vb[0] = ((const float4*)(xp + 32))[0];
    *(float4*)&vb[4] = ((const float4*)(xp + 32))[1];
    int k0 = q * 8;
    #pragma unroll
    for (int jj = 0; jj < 8; jj++) {
      float v = fmaxf(va[jj] * bnsc[k0 + jj] + bnsh[k0 + jj], 0.f);
      float w = fmaxf(vb[jj] * bnsc[k0 + 32 + jj] + bnsh[k0 + 32 + jj], 0.f);
      a0[jj] = (short)f2bf(v);
      a1[jj] = (short)f2bf(w);
    }
  } else if (f32) {
    const float* xp = (const float*)x + (size_t)rowc * 64 + q * 8;
    float va[8], vb[8];
    *(float4*)&va[0] = ((const float4*)xp)[0];
    *(float4*)&va[4] = ((const float4*)xp)[1];
    *(float4*)&vb[0] = ((const float4*)(xp + 32))[0];
    *(float4*)&vb[4] = ((const float4*)(xp + 32))[1];
    #pragma unroll
    for (int jj = 0; jj < 8; jj++) {
      a0[jj] = (short)f2bf(va[jj]);
      a1[jj] = (short)f2bf(vb[jj]);
    }
  } else {
    const unsigned short* xp = (const unsigned short*)x + (size_t)rowc * 64 + q * 8;
    a0 = *(const bf16x8*)xp;
    a1 = *(const bf16x8*)(xp + 32);
  }

  f32x4 acc[17];
  #pragma unroll
  for (int tt = 0; tt < 17; tt++) acc[tt] = (f32x4){0.f, 0.f, 0.f, 0.f};
  #pragma unroll
  for (int tt = 0; tt < 17; tt++) {
    int c = tt * 16 + r16;
    bf16x8 b0 = *(const bf16x8*)&WTs[c * 68 + q * 8];
    bf16x8 b1 = *(const bf16x8*)&WTs[c * 68 + 32 + q * 8];
    acc[tt] = __builtin_amdgcn_mfma_f32_16x16x32_bf16(a0, b0, acc[tt], 0, 0, 0);
    acc[tt] = __builtin_amdgcn_mfma_f32_16x16x32_bf16(a1, b1, acc[tt], 0, 0, 0);
  }

  // epilogue 1: als/ald from tile 16
  {
    int obase = m0 + q * 4;
    #pragma unroll
    for (int rr = 0; rr < 4; rr++) {
      int orow = obase + rr;
      if (orow < N) {
        if (r16 < 4) als[orow * 4 + r16] = acc[16][rr];
        else if (r16 < 8) ald[orow * 4 + (r16 - 4)] = acc[16][rr];
      }
    }
  }
  // epilogue 2: 4 chunked passes, per-wave LDS repack (wave-internal, no barrier)
  unsigned short* rp = RP[wave];
  #pragma unroll
  for (int g4 = 0; g4 < 4; g4++) {
    #pragma unroll
    for (int tt2 = 0; tt2 < 4; tt2++) {
      int tile = g4 * 4 + tt2;
      #pragma unroll
      for (int rr = 0; rr < 4; rr++)
        rp[(q * 4 + rr) * 68 + tt2 * 16 + r16] = f2bf(acc[tile][rr]);
    }
    #pragma unroll
    for (int i = 0; i < 2; i++) {
      int g = i * 64 + lane;
      int r = g >> 3;          // row 0..15
      int grp = g & 7;         // uint4 group within 64-col chunk
      uint4 v = *(const uint4*)&rp[r * 68 + grp * 8];
      int orow = m0 + r;
      if (orow < N) ((uint4*)xh)[(size_t)orow * 32 + g4 * 8 + grp] = v;
    }
  }
}

// ---------------- per-dst-node softmax aggregation (one node/wave, 4-edge unroll) ----------------
__global__ __launch_bounds__(256) void agg_kernel(
    const unsigned short* __restrict__ xh,
    const float* __restrict__ als, const float* __restrict__ ald,
    const int* __restrict__ offsets, const int* __restrict__ csr_src,
    const void* __restrict__ bias, const int* __restrict__ flags,
    float* __restrict__ y, int N) {
  int lane = threadIdx.x & 63;
  int wid = threadIdx.x >> 6;
  int n = blockIdx.x * 4 + wid;
  if (n >= N) return;
  int h = lane >> 4;
  const uint2* xv = (const uint2*)xh;
  float ad = ald[n * 4 + h];
  float e = als[n * 4 + h] + ad;  // implicit self loop
  e = (e > 0.f) ? e : NEG_SLOPE * e;
  float p = __expf(e);
  float dsum = p;
  uint2 xs = xv[(size_t)n * 64 + lane];
  float a0 = p * asf(xs.x << 16), a1 = p * asf(xs.x & 0xffff0000u);
  float a2 = p * asf(xs.y << 16), a3 = p * asf(xs.y & 0xffff0000u);
  int beg = offsets[n], end = offsets[n + 1];
  int j = beg;
  for (; j + 4 <= end; j += 4) {
    int s0 = csr_src[j];
    int s1 = csr_src[j + 1];
    int s2 = csr_src[j + 2];
    int s3 = csr_src[j + 3];
    uint2 v0 = xv[(size_t)s0 * 64 + lane];
    uint2 v1 = xv[(size_t)s1 * 64 + lane];
    uint2 v2 = xv[(size_t)s2 * 64 + lane];
    uint2 v3 = xv[(size_t)s3 * 64 + lane];
    float e0 = als[s0 * 4 + h] + ad;
    float e1 = als[s1 * 4 + h] + ad;
    float e2 = als[s2 * 4 + h] + ad;
    float e3 = als[s3 * 4 + h] + ad;
    e0 = (e0 > 0.f) ? e0 : NEG_SLOPE * e0;
    e1 = (e1 > 0.f) ? e1 : NEG_SLOPE * e1;
    e2 = (e2 > 0.f) ? e2 : NEG_SLOPE * e2;
    e3 = (e3 > 0.f) ? e3 : NEG_SLOPE * e3;
    float p0 = __expf(e0);
    float p1 = __expf(e1);
    float p2 = __expf(e2);
    float p3 = __expf(e3);
    dsum += p0 + p1 + p2 + p3;
    a0 += p0 * asf(v0.x << 16) + p1 * asf(v1.x << 16)
        + p2 * asf(v2.x << 16) + p3 * asf(v3.x << 16);
    a1 += p0 * asf(v0.x & 0xffff0000u) + p1 * asf(v1.x & 0xffff0000u)
        + p2 * asf(v2.x & 0xffff0000u) + p3 * asf(v3.x & 0xffff0000u);
    a2 += p0 * asf(v0.y << 16) + p1 * asf(v1.y << 16)
        + p2 * asf(v2.y << 16) + p3 * asf(v3.y << 16);
    a3 += p0 * asf(v0.y & 0xffff0000u) + p1 * asf(v1.y & 0xffff0000u)
        + p2 * asf(v2.y & 0xffff0000u) + p3 * asf(v3.y & 0xffff0000u);
  }
  for (; j < end; j++) {
    int s0 = csr_src[j];
    uint2 v0 = xv[(size_t)s0 * 64 + lane];
    float e0 = als[s0 * 4 + h] + ad;
    e0 = (e0 > 0.f) ? e0 : NEG_SLOPE * e0;
    float p0 = __expf(e0);
    dsum += p0;
    a0 += p0 * asf(v0.x << 16);
    a1 += p0 * asf(v0.x & 0xffff0000u);
    a2 += p0 * asf(v0.y << 16);
    a3 += p0 * asf(v0.y & 0xffff0000u);
  }
  float inv = 1.0f / dsum;
  a0 *= inv; a1 *= inv; a2 *= inv; a3 *= inv;
  // mean over 4 heads
  a0 += __shfl_xor(a0, 16); a0 += __shfl_xor(a0, 32);
  a1 += __shfl_xor(a1, 16); a1 += __shfl_xor(a1, 32);
  a2 += __shfl_xor(a2, 16); a2 += __shfl_xor(a2, 32);
  a3 += __shfl_xor(a3, 16); a3 += __shfl_xor(a3, 32);
  if (lane < 16) {
    int f32 = flags[0];
    float4 o;
    o.x = 0.25f * a0 + loadF(bias, 4 * lane + 0, f32);
    o.y = 0.25f * a1 + loadF(bias, 4 * lane + 1, f32);
    o.z = 0.25f * a2 + loadF(bias, 4 * lane + 2, f32);
    o.w = 0.25f * a3 + loadF(bias, 4 * lane + 3, f32);
    ((float4*)(y + (size_t)n * 64))[lane] = o;
  }
}

// ---------------- BN stats (per-channel sum / sumsq) ----------------
__global__ __launch_bounds__(256) void stats_kernel(const float* __restrict__ y,
                                                    float* __restrict__ gsum,
                                                    float* __restrict__ gsq, int N) {
  __shared__ float ls[256], lq[256];
  int t = threadIdx.x;
  int c = t & 63;
  int r0 = blockIdx.x * 4 + (t >> 6);
  float s = 0.f, q = 0.f;
  for (int r = r0; r < N; r += gridDim.x * 4) {
    float v = y[(size_t)r * 64 + c];
    s += v; q += v * v;
  }
  ls[t] = s; lq[t] = q;
  __syncthreads();
  if (t < 64) {
    s = ls[t] + ls[t + 64] + ls[t + 128] + ls[t + 192];
    q = lq[t] + lq[t + 64] + lq[t + 128] + lq[t + 192];
    atomicAdd(&gsum[c], s);
    atomicAdd(&gsq[c], q);
  }
}

// ---------------- BN apply + ReLU (final output only) ----------------
__global__ __launch_bounds__(256) void bn_kernel(
    const float* __restrict__ y, const float* __restrict__ gsum, const float* __restrict__ gsq,
    const void* __restrict__ gamma, const void* __restrict__ beta,
    const int* __restrict__ flags, float* __restrict__ out_f, int N) {
  int i = blockIdx.x * 256 + threadIdx.x;
  if (i >= N * 16) return;
  int f32 = flags[0];
  int cg = i & 15;
  float4 v = ((const float4*)y)[i];
  float4 s = ((const float4*)gsum)[cg];
  float4 q = ((const float4*)gsq)[cg];
  float inv_n = 1.0f / (float)N;
  float vv[4] = {v.x, v.y, v.z, v.w};
  float ss[4] = {s.x, s.y, s.z, s.w};
  float qq[4] = {q.x, q.y, q.z, q.w};
  float o[4];
  #pragma unroll
  for (int k = 0; k < 4; k++) {
    float g = loadF(gamma, 4 * cg + k, f32);
    float b = loadF(beta, 4 * cg + k, f32);
    float mu = ss[k] * inv_n;
    float var = fmaxf(qq[k] * inv_n - mu * mu, 0.f);
    float r = g * (vv[k] - mu) * rsqrtf(var + BN_EPS) + b;
    o[k] = r > 0.f ? r : 0.f;
  }
  float4 ov; ov.x = o[0]; ov.y = o[1]; ov.z = o[2]; ov.w = o[3];
  ((float4*)out_f)[i] = ov;
}

// ---------------- launch ----------------
extern "C" void kernel_launch(void* const* d_in, const int* in_sizes, int n_in,
                              void* d_out, int out_size, void* d_ws, size_t ws_size,
                              hipStream_t stream) {
  const void* x    = d_in[0];
  const void* ei   = d_in[1];
  const void* W0    = d_in[3];
  const void* asrc0 = d_in[4];
  const void* adst0 = d_in[5];
  const void* b0    = d_in[6];
  const void* g0    = d_in[7];
  const void* be0   = d_in[8];
  const void* W1    = d_in[9];
  const void* asrc1 = d_in[10];
  const void* adst1 = d_in[11];
  const void* b1    = d_in[12];
  const void* g1    = d_in[13];
  const void* be1   = d_in[14];

  int N = in_sizes[0] / 64;
  int E = in_sizes[1] / 2;
  int NB = (N + 255) / 256;   // scan blocks
  int NG = (N + 63) / 64;     // gemm blocks
  int NA = (N + 3) / 4;       // agg blocks: one node per wave

  char* p = (char*)d_ws;
  auto alloc = [&](size_t bytes) -> char* {
    char* r = p;
    p += (bytes + 255) & ~(size_t)255;
    return r;
  };
  int* flags    = (int*)alloc(256);
  int* deg      = (int*)alloc((size_t)N * 4);
  int* cursor   = (int*)alloc((size_t)N * 4);
  int* offsets  = (int*)alloc((size_t)(N + 1) * 4);
  int* blocksum = (int*)alloc((size_t)NB * 4);
  int* blockbase= (int*)alloc((size_t)(NB + 1) * 4);
  int* csr_src  = (int*)alloc((size_t)E * 4);
  unsigned short* WTx0 = (unsigned short*)alloc(272 * 64 * 2);
  unsigned short* WTx1 = (unsigned short*)alloc(272 * 64 * 2);
  unsigned short* xh = (unsigned short*)alloc((size_t)N * 256 * 2);
  float* als    = (float*)alloc((size_t)N * 4 * 4);
  float* ald    = (float*)alloc((size_t)N * 4 * 4);
  float* y      = (float*)alloc((size_t)N * 64 * 4);
  float* gsum0  = (float*)alloc(256);
  float* gsq0   = (float*)alloc(256);
  float* gsum1  = (float*)alloc(256);
  float* gsq1   = (float*)alloc(256);

  hipMemsetAsync(deg, 0, (size_t)N * 4, stream);
  hipMemsetAsync(cursor, 0, (size_t)N * 4, stream);
  hipMemsetAsync(gsum0, 0, 1024, stream);  // gsum0..gsq1 contiguous

  detect_kernel<<<1, 256, 0, stream>>>((const unsigned short*)x, (const int*)ei, flags);
  wtrans_kernel<<<2, 256, 0, stream>>>(W0, asrc0, adst0, W1, asrc1, adst1, flags, WTx0, WTx1);

  hist_kernel<<<(E + 255) / 256, 256, 0, stream>>>(ei, E, N, flags, deg);
  partial_kernel<<<NB, 256, 0, stream>>>(deg, blocksum, N);
  scan_base_kernel<<<1, 64, 0, stream>>>(blocksum, blockbase, NB);
  scan_final_kernel<<<NB, 256, 0, stream>>>(deg, blockbase, offsets, N);
  scatter_kernel<<<(E + 255) / 256, 256, 0, stream>>>(ei, E, N, flags, offsets, cursor, csr_src);

  float* out_x = (float*)d_out;                    // output 0: final, fp32
  float* out_saved = out_x + (size_t)N * 64;       // output 1: layer-2 pre-BN, fp32

  // ---- layer 0 ----
  gemm_mfma<<<NG, 256, 0, stream>>>(x, WTx0, flags, 0, (const float*)nullptr,
                                    (const float*)nullptr, nullptr, nullptr,
                                    xh, als, ald, N);
  agg_kernel<<<NA, 256, 0, stream>>>(xh, als, ald, offsets, csr_src, b0, flags, y, N);
  stats_kernel<<<250, 256, 0, stream>>>(y, gsum0, gsq0, N);
  // ---- layer 1 (BN of layer 0 fused into gemm A-load) ----
  gemm_mfma<<<NG, 256, 0, stream>>>(y, WTx1, flags, 1, gsum0, gsq0, g0, be0,
                                    xh, als, ald, N);
  agg_kernel<<<NA, 256, 0, stream>>>(xh, als, ald, offsets, csr_src, b1, flags, out_saved, N);
  stats_kernel<<<250, 256, 0, stream>>>(out_saved, gsum1, gsq1, N);
  bn_kernel<<<(N * 16 + 255) / 256, 256, 0, stream>>>(out_saved, gsum1, gsq1, g1, be1,
                                                      flags, out_x, N);
}

// Round 11
// 419.409 us; speedup vs baseline: 1.2602x; 1.0217x over previous
//
#include <hip/hip_runtime.h>
#include <stdint.h>

#define NEG_SLOPE 0.2f
#define BN_EPS 1e-5f

typedef __attribute__((ext_vector_type(8))) short bf16x8;
typedef __attribute__((ext_vector_type(4))) float f32x4;

// ---------------- bf16 helpers ----------------
__device__ __forceinline__ float bf2f(unsigned short u) {
  union { unsigned int i; float f; } v; v.i = ((unsigned int)u) << 16; return v.f;
}
__device__ __forceinline__ float asf(unsigned int u) {
  union { unsigned int i; float f; } v; v.i = u; return v.f;
}
__device__ __forceinline__ unsigned short f2bf(float f) {
  union { float f; unsigned int i; } v; v.f = f;
  unsigned int i = v.i;
  return (unsigned short)((i + 0x7fffu + ((i >> 16) & 1u)) >> 16);  // RNE
}
__device__ __forceinline__ float loadF(const void* p, long long i, int f32) {
  return f32 ? ((const float*)p)[i] : bf2f(((const unsigned short*)p)[i]);
}
__device__ __forceinline__ int edge_at(const void* ei, long long idx, int is64) {
  return is64 ? (int)((const long long*)ei)[idx] : ((const int*)ei)[idx];
}

// ---------------- input dtype detection ----------------
__global__ void detect_kernel(const unsigned short* __restrict__ x,
                              const int* __restrict__ ei32,
                              int* __restrict__ flags) {
  __shared__ int wild, oddnz;
  if (threadIdx.x == 0) { wild = 0; oddnz = 0; }
  __syncthreads();
  int lw = 0, lo = 0;
  for (int i = threadIdx.x; i < 4096; i += 256) {
    unsigned short u = x[i];
    int ex = (u >> 7) & 0xFF;
    if (ex >= 0x86) lw++;
    if (ei32[2 * i + 1] != 0) lo++;
  }
  if (lw) atomicAdd(&wild, lw);
  if (lo) atomicAdd(&oddnz, lo);
  __syncthreads();
  if (threadIdx.x == 0) { flags[0] = (wild > 64) ? 1 : 0; flags[1] = (oddnz == 0) ? 1 : 0; }
}

// ---------------- W preprocessing ----------------
// WTx [272 rows][64 k] bf16: rows 0..255 = W^T; 256..259 = Ws[h]; 260..263 = Wd[h]; 264..271 = 0.
__global__ __launch_bounds__(256) void wtrans_kernel(
    const void* __restrict__ W0, const void* __restrict__ as0, const void* __restrict__ ad0,
    const void* __restrict__ W1, const void* __restrict__ as1, const void* __restrict__ ad1,
    const int* __restrict__ flags,
    unsigned short* __restrict__ WTx0, unsigned short* __restrict__ WTx1) {
  const void* W = blockIdx.x ? W1 : W0;
  const void* asrc = blockIdx.x ? as1 : as0;
  const void* adst = blockIdx.x ? ad1 : ad0;
  unsigned short* WTx = blockIdx.x ? WTx1 : WTx0;
  int f32 = flags[0];
  __shared__ unsigned short Wl[64 * 258];
  int t = threadIdx.x;
  for (int i = t; i < 64 * 256; i += 256) {
    int k = i >> 8, c = i & 255;
    Wl[k * 258 + c] = f32 ? f2bf(((const float*)W)[i]) : ((const unsigned short*)W)[i];
  }
  __syncthreads();
  {
    int c = t;
    #pragma unroll
    for (int k8 = 0; k8 < 64; k8 += 8) {
      unsigned int p0 = (unsigned int)Wl[(k8 + 0) * 258 + c] | ((unsigned int)Wl[(k8 + 1) * 258 + c] << 16);
      unsigned int p1 = (unsigned int)Wl[(k8 + 2) * 258 + c] | ((unsigned int)Wl[(k8 + 3) * 258 + c] << 16);
      unsigned int p2 = (unsigned int)Wl[(k8 + 4) * 258 + c] | ((unsigned int)Wl[(k8 + 5) * 258 + c] << 16);
      unsigned int p3 = (unsigned int)Wl[(k8 + 6) * 258 + c] | ((unsigned int)Wl[(k8 + 7) * 258 + c] << 16);
      uint4 pk; pk.x = p0; pk.y = p1; pk.z = p2; pk.w = p3;
      *(uint4*)&WTx[c * 64 + k8] = pk;
    }
  }
  for (int idx = t; idx < 512; idx += 256) {
    int r = idx >> 6;
    int k = idx & 63;
    int h = r & 3;
    const void* av = (r >> 2) ? adst : asrc;
    float acc = 0.f;
    #pragma unroll 8
    for (int c = 0; c < 64; c++)
      acc += bf2f(Wl[k * 258 + h * 64 + c]) * loadF(av, h * 64 + c, f32);
    WTx[(256 + r) * 64 + k] = f2bf(acc);
  }
  for (int idx = t; idx < 512; idx += 256) WTx[264 * 64 + idx] = 0;
}

// ---------------- CSR build ----------------
__global__ __launch_bounds__(256) void hist_kernel(const void* __restrict__ ei, int E, int N,
                                                   const int* __restrict__ flags,
                                                   int* __restrict__ deg) {
  int e = blockIdx.x * 256 + threadIdx.x;
  if (e >= E) return;
  int is64 = flags[1];
  int d = edge_at(ei, (long long)E + e, is64);
  d = (d < 0 || d >= N) ? 0 : d;
  atomicAdd(&deg[d], 1);
}

__global__ __launch_bounds__(256) void partial_kernel(const int* __restrict__ deg,
                                                      int* __restrict__ blocksum, int N) {
  int t = threadIdx.x;
  int idx = blockIdx.x * 256 + t;
  int v = (idx < N) ? deg[idx] : 0;
  #pragma unroll
  for (int o = 1; o < 64; o <<= 1) v += __shfl_xor(v, o);
  __shared__ int ws[4];
  if ((t & 63) == 0) ws[t >> 6] = v;
  __syncthreads();
  if (t == 0) blocksum[blockIdx.x] = ws[0] + ws[1] + ws[2] + ws[3];
}

__global__ void scan_base_kernel(const int* __restrict__ blocksum,
                                 int* __restrict__ blockbase, int B) {
  int lane = threadIdx.x;
  int base = 0;
  if (lane == 0) blockbase[0] = 0;
  for (int start = 0; start < B; start += 64) {
    int idx = start + lane;
    int v = (idx < B) ? blocksum[idx] : 0;
    int sc = v;
    #pragma unroll
    for (int o = 1; o < 64; o <<= 1) {
      int u = __shfl_up(sc, o);
      if (lane >= o) sc += u;
    }
    if (idx < B) blockbase[idx + 1] = base + sc;
    base = __shfl(base + sc, 63);
  }
}

__global__ __launch_bounds__(256) void scan_final_kernel(const int* __restrict__ deg,
                                                         const int* __restrict__ blockbase,
                                                         int* __restrict__ offsets, int N) {
  int t = threadIdx.x;
  int lane = t & 63;
  int wid = t >> 6;
  int idx = blockIdx.x * 256 + t;
  int v = (idx < N) ? deg[idx] : 0;
  int sc = v;
  #pragma unroll
  for (int o = 1; o < 64; o <<= 1) {
    int u = __shfl_up(sc, o);
    if (lane >= o) sc += u;
  }
  __shared__ int ws[4];
  if (lane == 63) ws[wid] = sc;
  __syncthreads();
  int add = 0;
  #pragma unroll
  for (int w = 0; w < 4; w++) if (w < wid) add += ws[w];
  if (idx < N) offsets[idx + 1] = blockbase[blockIdx.x] + add + sc;
  if (idx == 0) offsets[0] = 0;
}

__global__ __launch_bounds__(256) void scatter_kernel(
    const void* __restrict__ ei, int E, int N, const int* __restrict__ flags,
    const int* __restrict__ offsets, int* __restrict__ cursor,
    int* __restrict__ csr_src) {
  int e = blockIdx.x * 256 + threadIdx.x;
  if (e >= E) return;
  int is64 = flags[1];
  int s = edge_at(ei, e, is64);
  int d = edge_at(ei, (long long)E + e, is64);
  s = (s < 0 || s >= N) ? 0 : s;
  d = (d < 0 || d >= N) ? 0 : d;
  int pos = offsets[d] + atomicAdd(&cursor[d], 1);
  csr_src[pos] = s;
}

// ---------------- MFMA GEMM: xh = x @ W (bf16) + als/ald tile; optional fused BN ----------------
// 128 rows per block (2 row-tiles share one WTx staging). mode 1: BN+ReLU fused A-load.
__global__ __launch_bounds__(256, 3) void gemm_mfma(
    const void* __restrict__ x, const unsigned short* __restrict__ WTx,
    const int* __restrict__ flags, int mode,
    const float* __restrict__ gsum, const float* __restrict__ gsq,
    const void* __restrict__ gamma, const void* __restrict__ beta,
    unsigned short* __restrict__ xh, float* __restrict__ als, float* __restrict__ ald,
    int N) {
  __shared__ unsigned short WTs[272 * 68];    // 36 KB staged weights
  __shared__ unsigned short RP[4][16 * 68];   // per-wave repack chunk (8.5 KB)
  __shared__ float bnsc[64], bnsh[64];
  int f32 = flags[0];
  int t = threadIdx.x;
  for (int i = t; i < 272 * 8; i += 256) {
    int c = i >> 3, g = i & 7;
    uint4 v = ((const uint4*)WTx)[i];
    *(uint4*)&WTs[c * 68 + g * 8] = v;
  }
  if (mode == 1 && t < 64) {
    float mu = gsum[t] / (float)N;
    float var = fmaxf(gsq[t] / (float)N - mu * mu, 0.f);
    float sc = loadF(gamma, t, f32) * rsqrtf(var + BN_EPS);
    bnsc[t] = sc;
    bnsh[t] = loadF(beta, t, f32) - mu * sc;
  }
  __syncthreads();

  int wave = t >> 6, lane = t & 63;
  int q = lane >> 4, r16 = lane & 15;
  unsigned short* rp = RP[wave];

  #pragma unroll
  for (int rb = 0; rb < 2; rb++) {
    int m0 = blockIdx.x * 128 + rb * 64 + wave * 16;
    if (m0 >= N) break;
    int row = m0 + r16;
    int rowc = row < N ? row : N - 1;

    bf16x8 a0, a1;
    if (mode == 1) {
      const float* xp = (const float*)x + (size_t)rowc * 64 + q * 8;
      float va[8], vb[8];
      *(float4*)&va[0] = ((const float4*)xp)[0];
      *(float4*)&va[4] = ((const float4*)xp)[1];
      *(float4*)&vb[0] = ((const float4*)(xp + 32))[0];
      *(float4*)&vb[4] = ((const float4*)(xp + 32))[1];
      int k0 = q * 8;
      #pragma unroll
      for (int jj = 0; jj < 8; jj++) {
        float v = fmaxf(va[jj] * bnsc[k0 + jj] + bnsh[k0 + jj], 0.f);
        float w = fmaxf(vb[jj] * bnsc[k0 + 32 + jj] + bnsh[k0 + 32 + jj], 0.f);
        a0[jj] = (short)f2bf(v);
        a1[jj] = (short)f2bf(w);
      }
    } else if (f32) {
      const float* xp = (const float*)x + (size_t)rowc * 64 + q * 8;
      float va[8], vb[8];
      *(float4*)&va[0] = ((const float4*)xp)[0];
      *(float4*)&va[4] = ((const float4*)xp)[1];
      *(float4*)&vb[0] = ((const float4*)(xp + 32))[0];
      *(float4*)&vb[4] = ((const float4*)(xp + 32))[1];
      #pragma unroll
      for (int jj = 0; jj < 8; jj++) {
        a0[jj] = (short)f2bf(va[jj]);
        a1[jj] = (short)f2bf(vb[jj]);
      }
    } else {
      const unsigned short* xp = (const unsigned short*)x + (size_t)rowc * 64 + q * 8;
      a0 = *(const bf16x8*)xp;
      a1 = *(const bf16x8*)(xp + 32);
    }

    f32x4 acc[17];
    #pragma unroll
    for (int tt = 0; tt < 17; tt++) acc[tt] = (f32x4){0.f, 0.f, 0.f, 0.f};
    #pragma unroll
    for (int tt = 0; tt < 17; tt++) {
      int c = tt * 16 + r16;
      bf16x8 b0 = *(const bf16x8*)&WTs[c * 68 + q * 8];
      bf16x8 b1 = *(const bf16x8*)&WTs[c * 68 + 32 + q * 8];
      acc[tt] = __builtin_amdgcn_mfma_f32_16x16x32_bf16(a0, b0, acc[tt], 0, 0, 0);
      acc[tt] = __builtin_amdgcn_mfma_f32_16x16x32_bf16(a1, b1, acc[tt], 0, 0, 0);
    }

    // epilogue 1: als/ald from tile 16
    {
      int obase = m0 + q * 4;
      #pragma unroll
      for (int rr = 0; rr < 4; rr++) {
        int orow = obase + rr;
        if (orow < N) {
          if (r16 < 4) als[orow * 4 + r16] = acc[16][rr];
          else if (r16 < 8) ald[orow * 4 + (r16 - 4)] = acc[16][rr];
        }
      }
    }
    // epilogue 2: 4 chunked passes, per-wave LDS repack (wave-internal, no barrier)
    #pragma unroll
    for (int g4 = 0; g4 < 4; g4++) {
      #pragma unroll
      for (int tt2 = 0; tt2 < 4; tt2++) {
        int tile = g4 * 4 + tt2;
        #pragma unroll
        for (int rr = 0; rr < 4; rr++)
          rp[(q * 4 + rr) * 68 + tt2 * 16 + r16] = f2bf(acc[tile][rr]);
      }
      #pragma unroll
      for (int i = 0; i < 2; i++) {
        int g = i * 64 + lane;
        int r = g >> 3;
        int grp = g & 7;
        uint4 v = *(const uint4*)&rp[r * 68 + grp * 8];
        int orow = m0 + r;
        if (orow < N) ((uint4*)xh)[(size_t)orow * 32 + g4 * 8 + grp] = v;
      }
    }
  }
}

// ---------------- per-dst-node softmax aggregation ----------------
// One node per wave (one-shot frame). Half-wave edge pairing: half = lane>>5 handles
// even/odd edge slots; lane covers 8 channels (uint4). 8 edges per unrolled iter.
__global__ __launch_bounds__(256) void agg_kernel(
    const unsigned short* __restrict__ xh,
    const float* __restrict__ als, const float* __restrict__ ald,
    const int* __restrict__ offsets, const int* __restrict__ csr_src,
    const void* __restrict__ bias, const int* __restrict__ flags,
    float* __restrict__ y, int N) {
  int lane = threadIdx.x & 63;
  int wid = threadIdx.x >> 6;
  int n = blockIdx.x * 4 + wid;
  if (n >= N) return;
  int half = lane >> 5;     // 0: even slots + self, 1: odd slots
  int hl = lane & 31;       // channels 8*hl .. 8*hl+7
  int h = hl >> 3;          // head
  const uint4* xv = (const uint4*)xh;
  float ad = ald[n * 4 + h];
  float acc0 = 0.f, acc1 = 0.f, acc2 = 0.f, acc3 = 0.f;
  float acc4 = 0.f, acc5 = 0.f, acc6 = 0.f, acc7 = 0.f;
  float dsum = 0.f;
  if (half == 0) {  // implicit self loop
    float e = als[n * 4 + h] + ad;
    e = (e > 0.f) ? e : NEG_SLOPE * e;
    float p = __expf(e);
    dsum = p;
    uint4 v = xv[(size_t)n * 32 + hl];
    acc0 = p * asf(v.x << 16); acc1 = p * asf(v.x & 0xffff0000u);
    acc2 = p * asf(v.y << 16); acc3 = p * asf(v.y & 0xffff0000u);
    acc4 = p * asf(v.z << 16); acc5 = p * asf(v.z & 0xffff0000u);
    acc6 = p * asf(v.w << 16); acc7 = p * asf(v.w & 0xffff0000u);
  }
  int beg = offsets[n], end = offsets[n + 1];
  int j = beg;
  for (; j + 8 <= end; j += 8) {
    int s0 = csr_src[j + 0 + half];
    int s1 = csr_src[j + 2 + half];
    int s2 = csr_src[j + 4 + half];
    int s3 = csr_src[j + 6 + half];
    uint4 v0 = xv[(size_t)s0 * 32 + hl];
    uint4 v1 = xv[(size_t)s1 * 32 + hl];
    uint4 v2 = xv[(size_t)s2 * 32 + hl];
    uint4 v3 = xv[(size_t)s3 * 32 + hl];
    float e0 = als[s0 * 4 + h] + ad;
    float e1 = als[s1 * 4 + h] + ad;
    float e2 = als[s2 * 4 + h] + ad;
    float e3 = als[s3 * 4 + h] + ad;
    e0 = (e0 > 0.f) ? e0 : NEG_SLOPE * e0;
    e1 = (e1 > 0.f) ? e1 : NEG_SLOPE * e1;
    e2 = (e2 > 0.f) ? e2 : NEG_SLOPE * e2;
    e3 = (e3 > 0.f) ? e3 : NEG_SLOPE * e3;
    float p0 = __expf(e0);
    float p1 = __expf(e1);
    float p2 = __expf(e2);
    float p3 = __expf(e3);
    dsum += p0 + p1 + p2 + p3;
    acc0 += p0 * asf(v0.x << 16) + p1 * asf(v1.x << 16)
          + p2 * asf(v2.x << 16) + p3 * asf(v3.x << 16);
    acc1 += p0 * asf(v0.x & 0xffff0000u) + p1 * asf(v1.x & 0xffff0000u)
          + p2 * asf(v2.x & 0xffff0000u) + p3 * asf(v3.x & 0xffff0000u);
    acc2 += p0 * asf(v0.y << 16) + p1 * asf(v1.y << 16)
          + p2 * asf(v2.y << 16) + p3 * asf(v3.y << 16);
    acc3 += p0 * asf(v0.y & 0xffff0000u) + p1 * asf(v1.y & 0xffff0000u)
          + p2 * asf(v2.y & 0xffff0000u) + p3 * asf(v3.y & 0xffff0000u);
    acc4 += p0 * asf(v0.z << 16) + p1 * asf(v1.z << 16)
          + p2 * asf(v2.z << 16) + p3 * asf(v3.z << 16);
    acc5 += p0 * asf(v0.z & 0xffff0000u) + p1 * asf(v1.z & 0xffff0000u)
          + p2 * asf(v2.z & 0xffff0000u) + p3 * asf(v3.z & 0xffff0000u);
    acc6 += p0 * asf(v0.w << 16) + p1 * asf(v1.w << 16)
          + p2 * asf(v2.w << 16) + p3 * asf(v3.w << 16);
    acc7 += p0 * asf(v0.w & 0xffff0000u) + p1 * asf(v1.w & 0xffff0000u)
          + p2 * asf(v2.w & 0xffff0000u) + p3 * asf(v3.w & 0xffff0000u);
  }
  for (; j < end; j += 2) {  // remainder: one edge per half
    int jj = j + half;
    if (jj < end) {
      int s = csr_src[jj];
      uint4 v = xv[(size_t)s * 32 + hl];
      float e = als[s * 4 + h] + ad;
      e = (e > 0.f) ? e : NEG_SLOPE * e;
      float p = __expf(e);
      dsum += p;
      acc0 += p * asf(v.x << 16); acc1 += p * asf(v.x & 0xffff0000u);
      acc2 += p * asf(v.y << 16); acc3 += p * asf(v.y & 0xffff0000u);
      acc4 += p * asf(v.z << 16); acc5 += p * asf(v.z & 0xffff0000u);
      acc6 += p * asf(v.w << 16); acc7 += p * asf(v.w & 0xffff0000u);
    }
  }
  // combine halves
  dsum += __shfl_xor(dsum, 32);
  acc0 += __shfl_xor(acc0, 32); acc1 += __shfl_xor(acc1, 32);
  acc2 += __shfl_xor(acc2, 32); acc3 += __shfl_xor(acc3, 32);
  acc4 += __shfl_xor(acc4, 32); acc5 += __shfl_xor(acc5, 32);
  acc6 += __shfl_xor(acc6, 32); acc7 += __shfl_xor(acc7, 32);
  float inv = 1.0f / dsum;
  acc0 *= inv; acc1 *= inv; acc2 *= inv; acc3 *= inv;
  acc4 *= inv; acc5 *= inv; acc6 *= inv; acc7 *= inv;
  // mean over heads: channel c lives in lanes {hl&7, +8, +16, +24}
  acc0 += __shfl_xor(acc0, 8); acc0 += __shfl_xor(acc0, 16);
  acc1 += __shfl_xor(acc1, 8); acc1 += __shfl_xor(acc1, 16);
  acc2 += __shfl_xor(acc2, 8); acc2 += __shfl_xor(acc2, 16);
  acc3 += __shfl_xor(acc3, 8); acc3 += __shfl_xor(acc3, 16);
  acc4 += __shfl_xor(acc4, 8); acc4 += __shfl_xor(acc4, 16);
  acc5 += __shfl_xor(acc5, 8); acc5 += __shfl_xor(acc5, 16);
  acc6 += __shfl_xor(acc6, 8); acc6 += __shfl_xor(acc6, 16);
  acc7 += __shfl_xor(acc7, 8); acc7 += __shfl_xor(acc7, 16);
  if (lane < 8) {
    int f32 = flags[0];
    int cb = 8 * lane;
    float4 o0, o1;
    o0.x = 0.25f * acc0 + loadF(bias, cb + 0, f32);
    o0.y = 0.25f * acc1 + loadF(bias, cb + 1, f32);
    o0.z = 0.25f * acc2 + loadF(bias, cb + 2, f32);
    o0.w = 0.25f * acc3 + loadF(bias, cb + 3, f32);
    o1.x = 0.25f * acc4 + loadF(bias, cb + 4, f32);
    o1.y = 0.25f * acc5 + loadF(bias, cb + 5, f32);
    o1.z = 0.25f * acc6 + loadF(bias, cb + 6, f32);
    o1.w = 0.25f * acc7 + loadF(bias, cb + 7, f32);
    *(float4*)(y + (size_t)n * 64 + cb) = o0;
    *(float4*)(y + (size_t)n * 64 + cb + 4) = o1;
  }
}

// ---------------- BN stats (per-channel sum / sumsq) ----------------
__global__ __launch_bounds__(256) void stats_kernel(const float* __restrict__ y,
                                                    float* __restrict__ gsum,
                                                    float* __restrict__ gsq, int N) {
  __shared__ float ls[256], lq[256];
  int t = threadIdx.x;
  int c = t & 63;
  int r0 = blockIdx.x * 4 + (t >> 6);
  float s = 0.f, q = 0.f;
  for (int r = r0; r < N; r += gridDim.x * 4) {
    float v = y[(size_t)r * 64 + c];
    s += v; q += v * v;
  }
  ls[t] = s; lq[t] = q;
  __syncthreads();
  if (t < 64) {
    s = ls[t] + ls[t + 64] + ls[t + 128] + ls[t + 192];
    q = lq[t] + lq[t + 64] + lq[t + 128] + lq[t + 192];
    atomicAdd(&gsum[c], s);
    atomicAdd(&gsq[c], q);
  }
}

// ---------------- BN apply + ReLU (final output only) ----------------
__global__ __launch_bounds__(256) void bn_kernel(
    const float* __restrict__ y, const float* __restrict__ gsum, const float* __restrict__ gsq,
    const void* __restrict__ gamma, const void* __restrict__ beta,
    const int* __restrict__ flags, float* __restrict__ out_f, int N) {
  int i = blockIdx.x * 256 + threadIdx.x;
  if (i >= N * 16) return;
  int f32 = flags[0];
  int cg = i & 15;
  float4 v = ((const float4*)y)[i];
  float4 s = ((const float4*)gsum)[cg];
  float4 q = ((const float4*)gsq)[cg];
  float inv_n = 1.0f / (float)N;
  float vv[4] = {v.x, v.y, v.z, v.w};
  float ss[4] = {s.x, s.y, s.z, s.w};
  float qq[4] = {q.x, q.y, q.z, q.w};
  float o[4];
  #pragma unroll
  for (int k = 0; k < 4; k++) {
    float g = loadF(gamma, 4 * cg + k, f32);
    float b = loadF(beta, 4 * cg + k, f32);
    float mu = ss[k] * inv_n;
    float var = fmaxf(qq[k] * inv_n - mu * mu, 0.f);
    float r = g * (vv[k] - mu) * rsqrtf(var + BN_EPS) + b;
    o[k] = r > 0.f ? r : 0.f;
  }
  float4 ov; ov.x = o[0]; ov.y = o[1]; ov.z = o[2]; ov.w = o[3];
  ((float4*)out_f)[i] = ov;
}

// ---------------- launch ----------------
extern "C" void kernel_launch(void* const* d_in, const int* in_sizes, int n_in,
                              void* d_out, int out_size, void* d_ws, size_t ws_size,
                              hipStream_t stream) {
  const void* x    = d_in[0];
  const void* ei   = d_in[1];
  const void* W0    = d_in[3];
  const void* asrc0 = d_in[4];
  const void* adst0 = d_in[5];
  const void* b0    = d_in[6];
  const void* g0    = d_in[7];
  const void* be0   = d_in[8];
  const void* W1    = d_in[9];
  const void* asrc1 = d_in[10];
  const void* adst1 = d_in[11];
  const void* b1    = d_in[12];
  const void* g1    = d_in[13];
  const void* be1   = d_in[14];

  int N = in_sizes[0] / 64;
  int E = in_sizes[1] / 2;
  int NB = (N + 255) / 256;    // scan blocks
  int NG = (N + 127) / 128;    // gemm blocks (128 rows each)
  int NA = (N + 3) / 4;        // agg blocks: one node per wave

  char* p = (char*)d_ws;
  auto alloc = [&](size_t bytes) -> char* {
    char* r = p;
    p += (bytes + 255) & ~(size_t)255;
    return r;
  };
  int* flags    = (int*)alloc(256);
  int* deg      = (int*)alloc((size_t)N * 4);
  int* cursor   = (int*)alloc((size_t)N * 4);
  int* offsets  = (int*)alloc((size_t)(N + 1) * 4);
  int* blocksum = (int*)alloc((size_t)NB * 4);
  int* blockbase= (int*)alloc((size_t)(NB + 1) * 4);
  int* csr_src  = (int*)alloc((size_t)E * 4);
  unsigned short* WTx0 = (unsigned short*)alloc(272 * 64 * 2);
  unsigned short* WTx1 = (unsigned short*)alloc(272 * 64 * 2);
  unsigned short* xh = (unsigned short*)alloc((size_t)N * 256 * 2);
  float* als    = (float*)alloc((size_t)N * 4 * 4);
  float* ald    = (float*)alloc((size_t)N * 4 * 4);
  float* y      = (float*)alloc((size_t)N * 64 * 4);
  float* gsum0  = (float*)alloc(256);
  float* gsq0   = (float*)alloc(256);
  float* gsum1  = (float*)alloc(256);
  float* gsq1   = (float*)alloc(256);

  hipMemsetAsync(deg, 0, (size_t)N * 4, stream);
  hipMemsetAsync(cursor, 0, (size_t)N * 4, stream);
  hipMemsetAsync(gsum0, 0, 1024, stream);  // gsum0..gsq1 contiguous

  detect_kernel<<<1, 256, 0, stream>>>((const unsigned short*)x, (const int*)ei, flags);
  wtrans_kernel<<<2, 256, 0, stream>>>(W0, asrc0, adst0, W1, asrc1, adst1, flags, WTx0, WTx1);

  hist_kernel<<<(E + 255) / 256, 256, 0, stream>>>(ei, E, N, flags, deg);
  partial_kernel<<<NB, 256, 0, stream>>>(deg, blocksum, N);
  scan_base_kernel<<<1, 64, 0, stream>>>(blocksum, blockbase, NB);
  scan_final_kernel<<<NB, 256, 0, stream>>>(deg, blockbase, offsets, N);
  scatter_kernel<<<(E + 255) / 256, 256, 0, stream>>>(ei, E, N, flags, offsets, cursor, csr_src);

  float* out_x = (float*)d_out;                    // output 0: final, fp32
  float* out_saved = out_x + (size_t)N * 64;       // output 1: layer-2 pre-BN, fp32

  // ---- layer 0 ----
  gemm_mfma<<<NG, 256, 0, stream>>>(x, WTx0, flags, 0, (const float*)nullptr,
                                    (const float*)nullptr, nullptr, nullptr,
                                    xh, als, ald, N);
  agg_kernel<<<NA, 256, 0, stream>>>(xh, als, ald, offsets, csr_src, b0, flags, y, N);
  stats_kernel<<<250, 256, 0, stream>>>(y, gsum0, gsq0, N);
  // ---- layer 1 (BN of layer 0 fused into gemm A-load) ----
  gemm_mfma<<<NG, 256, 0, stream>>>(y, WTx1, flags, 1, gsum0, gsq0, g0, be0,
                                    xh, als, ald, N);
  agg_kernel<<<NA, 256, 0, stream>>>(xh, als, ald, offsets, csr_src, b1, flags, out_saved, N);
  stats_kernel<<<250, 256, 0, stream>>>(out_saved, gsum1, gsq1, N);
  bn_kernel<<<(N * 16 + 255) / 256, 256, 0, stream>>>(out_saved, gsum1, gsq1, g1, be1,
                                                      flags, out_x, N);
}